// Round 6
// baseline (733.544 us; speedup 1.0000x reference)
//
#include <hip/hip_runtime.h>
#include <math.h>

#define Bb 8
#define Ss 2048
#define Ee 256
#define Hh 4
#define Dd 64

typedef unsigned short u16;
typedef unsigned int u32;
typedef __attribute__((ext_vector_type(8))) short bf16x8;
typedef __attribute__((ext_vector_type(4))) float f32x4;
typedef __attribute__((ext_vector_type(16))) float f32x16;
typedef __attribute__((ext_vector_type(4))) u32 u32x4;

__device__ __forceinline__ u16 f2bf(float f) {
  union { float f; u32 u; } c; c.f = f;
  return (u16)((c.u + 0x7FFFu + ((c.u >> 16) & 1u)) >> 16);
}
__device__ __forceinline__ float bf2f(u16 u) {
  union { u32 u; float f; } c; c.u = ((u32)u) << 16;
  return c.f;
}
__device__ __forceinline__ float bf2fs(short s) { return bf2f((u16)s); }
__device__ __forceinline__ u32 cvtpk(float a, float b) {
  u32 r;
  asm("v_cvt_pk_bf16_f32 %0, %1, %2" : "=v"(r) : "v"(a), "v"(b));
  return r;
}
__device__ __forceinline__ float ex2(float x) { return __builtin_amdgcn_exp2f(x); }

// ---------------- weight fp32 -> bf16 convert ----------------
__global__ __launch_bounds__(256) void k_w2b(const float* __restrict__ src,
                                             u16* __restrict__ dst) {
  int idx = (blockIdx.x * 256 + threadIdx.x) * 4;
  float4 v = *reinterpret_cast<const float4*>(src + idx);
  ushort4 o;
  o.x = f2bf(v.x); o.y = f2bf(v.y); o.z = f2bf(v.z); o.w = f2bf(v.w);
  *reinterpret_cast<ushort4*>(dst + idx) = o;
}

// ---------------- embedding gather (fp32 x + bf16 xb) ----------------
__global__ __launch_bounds__(256) void k_gather(const int* __restrict__ seqs,
                                                const float* __restrict__ emb,
                                                float* __restrict__ x,
                                                u16* __restrict__ xb) {
  int idx = blockIdx.x * 256 + threadIdx.x;
  int row = idx >> 6, c4 = idx & 63;
  int tok = seqs[row];
  float4 v = reinterpret_cast<const float4*>(emb)[(size_t)tok * 64 + c4];
  reinterpret_cast<float4*>(x)[(size_t)row * 64 + c4] = v;
  ushort4 o;
  o.x = f2bf(v.x); o.y = f2bf(v.y); o.z = f2bf(v.z); o.w = f2bf(v.w);
  reinterpret_cast<ushort4*>(xb)[(size_t)row * 64 + c4] = o;
}

// ---------------- QKV projection (MFMA bf16): relu(xb@W^T+b) -> bf16 --------
// Q output pre-scaled by log2(e)/16 (folds attention scale AND exp->exp2).
__global__ __launch_bounds__(256) void k_qkvm(const u16* __restrict__ xb,
    const u16* __restrict__ Wqb, const u16* __restrict__ Wkb, const u16* __restrict__ Wvb,
    const float* __restrict__ bq, const float* __restrict__ bk, const float* __restrict__ bv,
    u16* __restrict__ Qf, u16* __restrict__ Kf, u16* __restrict__ Vf, int mod) {
  __shared__ short Xs[128][72];
  __shared__ short Ws[128][72];
  int tid = threadIdx.x;
  int bn = blockIdx.x;
  int arr = bn >> 1, coff = (bn & 1) << 7;
  const u16* W = (arr == 0 ? Wqb : arr == 1 ? Wkb : Wvb) + (size_t)mod * 256 * 256;
  const float* bias = (arr == 0 ? bq : arr == 1 ? bk : bv) + mod * 256;
  u16* Out = (arr == 0 ? Qf : arr == 1 ? Kf : Vf);
  float oscale = (arr == 0) ? 0.0625f * 1.44269504f : 1.0f;
  int s0 = blockIdx.y * 128;
  int lr = tid >> 1, lc = (tid & 1) << 5;
  int w = tid >> 6, lane = tid & 63, ml = lane & 15, q = lane >> 4;
  int sh = (w >> 1) << 6, th = (w & 1) << 6;
  f32x4 acc[4][4] = {};
  for (int k0 = 0; k0 < 256; k0 += 64) {
#pragma unroll
    for (int hh = 0; hh < 4; hh++) {
      *reinterpret_cast<bf16x8*>(&Xs[lr][lc + hh * 8]) =
          *reinterpret_cast<const bf16x8*>(xb + (size_t)(s0 + lr) * Ee + k0 + lc + hh * 8);
      *reinterpret_cast<bf16x8*>(&Ws[lr][lc + hh * 8]) =
          *reinterpret_cast<const bf16x8*>(W + (size_t)(coff + lr) * Ee + k0 + lc + hh * 8);
    }
    __syncthreads();
#pragma unroll
    for (int ks = 0; ks < 2; ks++) {
      bf16x8 af[4], bfr[4];
#pragma unroll
      for (int mt = 0; mt < 4; mt++)
        af[mt] = *reinterpret_cast<const bf16x8*>(&Xs[sh + mt * 16 + ml][ks * 32 + q * 8]);
#pragma unroll
      for (int nt = 0; nt < 4; nt++)
        bfr[nt] = *reinterpret_cast<const bf16x8*>(&Ws[th + nt * 16 + ml][ks * 32 + q * 8]);
#pragma unroll
      for (int mt = 0; mt < 4; mt++)
#pragma unroll
        for (int nt = 0; nt < 4; nt++)
          acc[mt][nt] = __builtin_amdgcn_mfma_f32_16x16x32_bf16(af[mt], bfr[nt], acc[mt][nt], 0, 0, 0);
    }
    __syncthreads();
  }
#pragma unroll
  for (int mt = 0; mt < 4; mt++)
#pragma unroll
    for (int nt = 0; nt < 4; nt++)
#pragma unroll
      for (int r = 0; r < 4; r++) {
        int gm = s0 + sh + mt * 16 + q * 4 + r;
        int cc = coff + th + nt * 16 + ml;
        float v = acc[mt][nt][r] + bias[cc];
        v = (v > 0.f ? v : 0.f) * oscale;
        Out[(size_t)gm * Ee + cc] = f2bf(v);
      }
}

// ---------------- V transpose: Vf[b][t][h*64+d] -> Vt[(b*4+h)*64+d][t] -------
__global__ __launch_bounds__(256) void k_vt(const u16* __restrict__ Vf,
                                            u16* __restrict__ Vt) {
  __shared__ u16 T[64][72];
  int tid = threadIdx.x;
  int t0 = blockIdx.x * 64;
  int z = blockIdx.y;
  int b = z >> 2, h = z & 3;
  int lr = tid >> 2, lc = (tid & 3) << 4;
#pragma unroll
  for (int hh = 0; hh < 2; hh++) {
    bf16x8 v = *reinterpret_cast<const bf16x8*>(
        Vf + (size_t)(b * Ss + t0 + lr) * Ee + h * Dd + lc + hh * 8);
#pragma unroll
    for (int j = 0; j < 8; j++) T[lr][lc + hh * 8 + j] = (u16)v[j];
  }
  __syncthreads();
#pragma unroll
  for (int j = 0; j < 16; j++) {
    Vt[((size_t)z * Dd + lr) * Ss + t0 + lc + j] = T[lc + j][lr];
  }
}

// ---------------- SV[z][d] = sum_t Vt[z*64+d][t]; also zero csums ------------
__global__ __launch_bounds__(256) void k_vsum(const u16* __restrict__ Vt,
                                              float* __restrict__ SV,
                                              float* __restrict__ csums) {
  int gi = (blockIdx.y * gridDim.x + blockIdx.x) * 256 + threadIdx.x;
  if (gi < 32 * Ss) csums[gi] = 0.f;
  int z = blockIdx.y;
  int d = blockIdx.x * 4 + (threadIdx.x >> 6);
  int lane = threadIdx.x & 63;
  const u16* row = Vt + ((size_t)z * Dd + d) * Ss;
  float s = 0.f;
#pragma unroll
  for (int it = 0; it < 4; it++) {
    bf16x8 v = *reinterpret_cast<const bf16x8*>(row + it * 512 + lane * 8);
#pragma unroll
    for (int j = 0; j < 8; j++) s += bf2fs(v[j]);
  }
#pragma unroll
  for (int off = 32; off; off >>= 1) s += __shfl_xor(s, off);
  if (lane == 0) SV[(size_t)z * Dd + d] = s;
}

// ---------------- pass 1: csums[t] += sum_s exp2(S) (barrier-free loop) ------
__global__ __launch_bounds__(256, 4) void k_csum(const u16* __restrict__ Qf,
    const u16* __restrict__ Kf, float* __restrict__ csums) {
  __shared__ float csm[2][128];
  int tid = threadIdx.x;
  int lin = (blockIdx.z * 2 + blockIdx.y) * 16 + blockIdx.x;
  int wgid = (lin & 7) * 128 + (lin >> 3);   // XCD-chunked, bijective (1024 % 8 == 0)
  int ttile = wgid & 15, shalf = (wgid >> 4) & 1, z = wgid >> 5;
  int b = z >> 2, h = z & 3;
  const u16* Qb = Qf + (size_t)b * Ss * Ee + h * Dd;
  const u16* Kb = Kf + (size_t)b * Ss * Ee + h * Dd;
  int w = tid >> 6, lane = tid & 63, l31 = lane & 31, hi = lane >> 5;
  int sh = (w >> 1) << 6, th = (w & 1) << 6;
  const u16* kr = Kb + (size_t)(ttile * 128 + th + l31) * Ee + hi * 8;
  bf16x8 kb[2][4];
#pragma unroll
  for (int tt = 0; tt < 2; tt++)
#pragma unroll
    for (int kk = 0; kk < 4; kk++)
      kb[tt][kk] = *reinterpret_cast<const bf16x8*>(kr + (size_t)tt * 32 * Ee + kk * 16);
  const u16* Qr0 = Qb + (size_t)(shalf * 1024 + sh + l31) * Ee + hi * 8;
  bf16x8 qc0 = *reinterpret_cast<const bf16x8*>(Qr0);
  bf16x8 qc1 = *reinterpret_cast<const bf16x8*>(Qr0 + 16);
  bf16x8 qc2 = *reinterpret_cast<const bf16x8*>(Qr0 + 32);
  bf16x8 qc3 = *reinterpret_cast<const bf16x8*>(Qr0 + 48);
  float cs0 = 0.f, cs1 = 0.f;
  for (int it = 0; it < 16; it++) {
    int itn = (it + 1) & 15;
    const u16* qnp = Qr0 + (size_t)(((itn >> 1) << 7) + ((itn & 1) << 5)) * Ee;
    bf16x8 qn0 = *reinterpret_cast<const bf16x8*>(qnp);
    bf16x8 qn1 = *reinterpret_cast<const bf16x8*>(qnp + 16);
    bf16x8 qn2 = *reinterpret_cast<const bf16x8*>(qnp + 32);
    bf16x8 qn3 = *reinterpret_cast<const bf16x8*>(qnp + 48);
    f32x16 a0 = {}, a1 = {};
    __builtin_amdgcn_s_setprio(1);
    a0 = __builtin_amdgcn_mfma_f32_32x32x16_bf16(qc0, kb[0][0], a0, 0, 0, 0);
    a1 = __builtin_amdgcn_mfma_f32_32x32x16_bf16(qc0, kb[1][0], a1, 0, 0, 0);
    a0 = __builtin_amdgcn_mfma_f32_32x32x16_bf16(qc1, kb[0][1], a0, 0, 0, 0);
    a1 = __builtin_amdgcn_mfma_f32_32x32x16_bf16(qc1, kb[1][1], a1, 0, 0, 0);
    a0 = __builtin_amdgcn_mfma_f32_32x32x16_bf16(qc2, kb[0][2], a0, 0, 0, 0);
    a1 = __builtin_amdgcn_mfma_f32_32x32x16_bf16(qc2, kb[1][2], a1, 0, 0, 0);
    a0 = __builtin_amdgcn_mfma_f32_32x32x16_bf16(qc3, kb[0][3], a0, 0, 0, 0);
    a1 = __builtin_amdgcn_mfma_f32_32x32x16_bf16(qc3, kb[1][3], a1, 0, 0, 0);
    __builtin_amdgcn_s_setprio(0);
#pragma unroll
    for (int j = 0; j < 16; j++) { cs0 += ex2(a0[j]); cs1 += ex2(a1[j]); }
    qc0 = qn0; qc1 = qn1; qc2 = qn2; qc3 = qn3;
  }
  cs0 += __shfl_xor(cs0, 32);
  cs1 += __shfl_xor(cs1, 32);
  if (lane < 32) {
    csm[w >> 1][th + l31] = cs0;
    csm[w >> 1][th + 32 + l31] = cs1;
  }
  __syncthreads();
  if (tid < 128)
    atomicAdd(&csums[(size_t)z * Ss + ttile * 128 + tid], csm[0][tid] + csm[1][tid]);
}

// ---------------- csums -> llic = -log2(csums), in place ---------------------
__global__ void k_llog(float* __restrict__ llic) {
  int i = blockIdx.x * 256 + threadIdx.x;
  llic[i] = -__log2f(llic[i]);
}

// ---------------- pass 2: fused attention, ZERO barriers in main loop --------
// grid (32 s-tiles of 64 rows, 32 z). Transposed QK (t on regs, s on lanes).
// P feeds PV's A-operand via pi(k) = (k&3)+8*((k>>2)&1)+4*(k>>3) mirrored in
// the per-lane V global-load addresses. K, V, llic ALL per-lane from global
// (L2/L3-hot, XCD swizzle) -> no LDS, no __syncthreads in the loop; waves run
// free and TLP hides latency. expm1 via exp2 (TRANS pipe) not poly4 (VALU).
// LDS only for the end cross-wave (tw) reduction.
__global__ __launch_bounds__(256, 3) void k_att(const u16* __restrict__ Qf,
    const u16* __restrict__ Kf, const u16* __restrict__ Vt,
    const float* __restrict__ llic, const float* __restrict__ SV,
    u16* __restrict__ Zb) {
  __shared__ float red[4][32][32];            // 16 KB (epilogue only)
  __shared__ float rs[2][2][32];              // 512 B
  int tid = threadIdx.x;
  int lin = blockIdx.y * 32 + blockIdx.x;
  int wgid = (lin & 7) * 128 + (lin >> 3);    // XCD-chunked, bijective
  int z = wgid >> 5, sblk = wgid & 31;
  int b = z >> 2, h = z & 3;
  const u16* Qb = Qf + (size_t)b * Ss * Ee + h * Dd;
  const u16* Kb = Kf + (size_t)b * Ss * Ee + h * Dd;
  const u16* VtZ = Vt + (size_t)z * Dd * Ss;
  const float* lz = llic + (size_t)z * Ss;
  int s0 = sblk * 64;
  int w = tid >> 6, lane = tid & 63;
  int l31 = lane & 31, hi = lane >> 5;
  int tw = w >> 1, sw = w & 1;
  // Q B-frags (loop-invariant)
  const u16* qrow = Qb + (size_t)(s0 + sw * 32 + l31) * Ee + hi * 8;
  bf16x8 qb0 = *reinterpret_cast<const bf16x8*>(qrow);
  bf16x8 qb1 = *reinterpret_cast<const bf16x8*>(qrow + 16);
  bf16x8 qb2 = *reinterpret_cast<const bf16x8*>(qrow + 32);
  bf16x8 qb3 = *reinterpret_cast<const bf16x8*>(qrow + 48);
  // per-lane bases
  const u16* krow = Kb + (size_t)(tw * 32 + l31) * Ee + hi * 8;  // + t0*Ee
  int tb0 = tw * 32 + 4 * hi;                 // t-col base within chunk
  const u16* vrow0 = VtZ + (size_t)l31 * Ss + tb0;        // + t0
  const u16* vrow1 = VtZ + (size_t)(32 + l31) * Ss + tb0; // + t0
  const float* lzp = lz + tb0;                            // + t0
  f32x16 acc20 = {}, acc21 = {};
  float rsv = 0.f;

  for (int t0 = 0; t0 < Ss; t0 += 64) {
    const u16* kc = krow + (size_t)t0 * Ee;
    bf16x8 kf0 = *reinterpret_cast<const bf16x8*>(kc);
    bf16x8 kf1 = *reinterpret_cast<const bf16x8*>(kc + 16);
    bf16x8 kf2 = *reinterpret_cast<const bf16x8*>(kc + 32);
    bf16x8 kf3 = *reinterpret_cast<const bf16x8*>(kc + 48);
    // V loads issue early (independent of QK result) to hide L2 latency
    const u16* v0p = vrow0 + t0;
    const u16* v1p = vrow1 + t0;
    uint2 u00 = *reinterpret_cast<const uint2*>(v0p);
    uint2 u01 = *reinterpret_cast<const uint2*>(v0p + 8);
    uint2 u02 = *reinterpret_cast<const uint2*>(v0p + 16);
    uint2 u03 = *reinterpret_cast<const uint2*>(v0p + 24);
    uint2 u10 = *reinterpret_cast<const uint2*>(v1p);
    uint2 u11 = *reinterpret_cast<const uint2*>(v1p + 8);
    uint2 u12 = *reinterpret_cast<const uint2*>(v1p + 16);
    uint2 u13 = *reinterpret_cast<const uint2*>(v1p + 24);
    float4 lc0 = *reinterpret_cast<const float4*>(lzp + t0);
    float4 lc1 = *reinterpret_cast<const float4*>(lzp + t0 + 8);
    float4 lc2 = *reinterpret_cast<const float4*>(lzp + t0 + 16);
    float4 lc3 = *reinterpret_cast<const float4*>(lzp + t0 + 24);
    f32x16 at = {};
    __builtin_amdgcn_s_setprio(1);
    at = __builtin_amdgcn_mfma_f32_32x32x16_bf16(kf0, qb0, at, 0, 0, 0);
    at = __builtin_amdgcn_mfma_f32_32x32x16_bf16(kf1, qb1, at, 0, 0, 0);
    at = __builtin_amdgcn_mfma_f32_32x32x16_bf16(kf2, qb2, at, 0, 0, 0);
    at = __builtin_amdgcn_mfma_f32_32x32x16_bf16(kf3, qb3, at, 0, 0, 0);
    __builtin_amdgcn_s_setprio(0);
    // transform: e1 = exp2(S + llic) in (0,1]; p = exp(e1)-1 via exp2 (TRANS)
    float4 lca[4] = {lc0, lc1, lc2, lc3};
    u32 pk[8];
#pragma unroll
    for (int g = 0; g < 4; g++) {
      float e0 = ex2(at[4 * g + 0] + lca[g].x);
      float e1 = ex2(at[4 * g + 1] + lca[g].y);
      float e2 = ex2(at[4 * g + 2] + lca[g].z);
      float e3 = ex2(at[4 * g + 3] + lca[g].w);
      float p0 = ex2(e0 * 1.44269504f) - 1.0f;
      float p1 = ex2(e1 * 1.44269504f) - 1.0f;
      float p2 = ex2(e2 * 1.44269504f) - 1.0f;
      float p3 = ex2(e3 * 1.44269504f) - 1.0f;
      rsv += (p0 + p1) + (p2 + p3);
      pk[2 * g] = cvtpk(p0, p1);
      pk[2 * g + 1] = cvtpk(p2, p3);
    }
    u32x4 aw0 = {pk[0], pk[1], pk[2], pk[3]};
    u32x4 aw1 = {pk[4], pk[5], pk[6], pk[7]};
    bf16x8 pa0 = __builtin_bit_cast(bf16x8, aw0);
    bf16x8 pa1 = __builtin_bit_cast(bf16x8, aw1);
    u32x4 bw00 = {u00.x, u00.y, u01.x, u01.y};
    u32x4 bw01 = {u02.x, u02.y, u03.x, u03.y};
    u32x4 bw10 = {u10.x, u10.y, u11.x, u11.y};
    u32x4 bw11 = {u12.x, u12.y, u13.x, u13.y};
    bf16x8 bv00 = __builtin_bit_cast(bf16x8, bw00);
    bf16x8 bv01 = __builtin_bit_cast(bf16x8, bw01);
    bf16x8 bv10 = __builtin_bit_cast(bf16x8, bw10);
    bf16x8 bv11 = __builtin_bit_cast(bf16x8, bw11);
    __builtin_amdgcn_s_setprio(1);
    acc20 = __builtin_amdgcn_mfma_f32_32x32x16_bf16(pa0, bv00, acc20, 0, 0, 0);
    acc20 = __builtin_amdgcn_mfma_f32_32x32x16_bf16(pa1, bv01, acc20, 0, 0, 0);
    acc21 = __builtin_amdgcn_mfma_f32_32x32x16_bf16(pa0, bv10, acc21, 0, 0, 0);
    acc21 = __builtin_amdgcn_mfma_f32_32x32x16_bf16(pa1, bv11, acc21, 0, 0, 0);
    __builtin_amdgcn_s_setprio(0);
  }

  // rowsum: combine hi-halves, publish per (tw, sw)
  rsv += __shfl_xor(rsv, 32);
  if (lane < 32) rs[tw][sw][l31] = rsv;
  // tw=1 waves publish partial O for cross-wave reduction
  if (tw == 1) {
#pragma unroll
    for (int r = 0; r < 16; r++) {
      int sl = (r & 3) + 8 * (r >> 2) + 4 * hi;
      red[sw * 2 + 0][sl][l31] = acc20[r];
      red[sw * 2 + 1][sl][l31] = acc21[r];
    }
  }
  __syncthreads();
  if (tw == 0) {
    float svd0 = SV[(size_t)z * Dd + l31];
    float svd1 = SV[(size_t)z * Dd + 32 + l31];
#pragma unroll
    for (int r = 0; r < 16; r++) {
      int sl = (r & 3) + 8 * (r >> 2) + 4 * hi;
      float rsum = rs[0][sw][sl] + rs[1][sw][sl];
      float inv = 1.f / (2048.f + rsum);
      float o0 = (svd0 + acc20[r] + red[sw * 2 + 0][sl][l31]) * inv;
      float o1 = (svd1 + acc21[r] + red[sw * 2 + 1][sl][l31]) * inv;
      size_t orow = (size_t)(b * Ss + s0 + sw * 32 + sl) * Ee + h * Dd;
      Zb[orow + l31] = f2bf(o0);
      Zb[orow + 32 + l31] = f2bf(o1);
    }
  }
}

// ---------------- ZF (MFMA bf16) + residual: x += Zb@Wz^T + bz; xb refresh ---
__global__ __launch_bounds__(256) void k_zfm(const u16* __restrict__ Zb,
    const u16* __restrict__ Wzb, const float* __restrict__ bzp,
    float* __restrict__ x, u16* __restrict__ xb, int mod) {
  __shared__ short Zs[128][72];
  __shared__ short Ws[128][72];
  int tid = threadIdx.x;
  int coff = blockIdx.x << 7;
  const u16* W = Wzb + (size_t)mod * 256 * 256;
  const float* bias = bzp + mod * Ee;
  int s0 = blockIdx.y * 128;
  int lr = tid >> 1, lc = (tid & 1) << 5;
  int w = tid >> 6, lane = tid & 63, ml = lane & 15, q = lane >> 4;
  int sh = (w >> 1) << 6, th = (w & 1) << 6;
  f32x4 acc[4][4] = {};
  for (int k0 = 0; k0 < 256; k0 += 64) {
#pragma unroll
    for (int hh = 0; hh < 4; hh++) {
      *reinterpret_cast<bf16x8*>(&Zs[lr][lc + hh * 8]) =
          *reinterpret_cast<const bf16x8*>(Zb + (size_t)(s0 + lr) * Ee + k0 + lc + hh * 8);
      *reinterpret_cast<bf16x8*>(&Ws[lr][lc + hh * 8]) =
          *reinterpret_cast<const bf16x8*>(W + (size_t)(coff + lr) * Ee + k0 + lc + hh * 8);
    }
    __syncthreads();
#pragma unroll
    for (int ks = 0; ks < 2; ks++) {
      bf16x8 af[4], bfr[4];
#pragma unroll
      for (int mt = 0; mt < 4; mt++)
        af[mt] = *reinterpret_cast<const bf16x8*>(&Zs[sh + mt * 16 + ml][ks * 32 + q * 8]);
#pragma unroll
      for (int nt = 0; nt < 4; nt++)
        bfr[nt] = *reinterpret_cast<const bf16x8*>(&Ws[th + nt * 16 + ml][ks * 32 + q * 8]);
#pragma unroll
      for (int mt = 0; mt < 4; mt++)
#pragma unroll
        for (int nt = 0; nt < 4; nt++)
          acc[mt][nt] = __builtin_amdgcn_mfma_f32_16x16x32_bf16(af[mt], bfr[nt], acc[mt][nt], 0, 0, 0);
    }
    __syncthreads();
  }
#pragma unroll
  for (int mt = 0; mt < 4; mt++)
#pragma unroll
    for (int nt = 0; nt < 4; nt++)
#pragma unroll
      for (int r = 0; r < 4; r++) {
        int gm = s0 + sh + mt * 16 + q * 4 + r;
        int gn = coff + th + nt * 16 + ml;
        float xv = x[(size_t)gm * Ee + gn] + acc[mt][nt][r] + bias[gn];
        x[(size_t)gm * Ee + gn] = xv;
        xb[(size_t)gm * Ee + gn] = f2bf(xv);
      }
}

// ---------------- final head: block = (c-chunk of 4096, 2 batches) -----------
__global__ __launch_bounds__(256) void k_final1(const float* __restrict__ x,
    const float* __restrict__ Wo, float* __restrict__ part) {
  int cb = blockIdx.x;                 // 0..127 chunk of 4096 floats
  int b0 = blockIdx.y * 2;             // 0,2,4,6
  int tid = threadIdx.x;
  int w = tid >> 6, lane = tid & 63;
  float acc[2][16];
#pragma unroll
  for (int bb = 0; bb < 2; bb++)
#pragma unroll
    for (int l = 0; l < 16; l++) acc[bb][l] = 0.f;
  const float4* x4 = reinterpret_cast<const float4*>(x);
  const float4* w4 = reinterpret_cast<const float4*>(Wo);
#pragma unroll
  for (int it = 0; it < 4; it++) {
    int i = it * 256 + tid;
    float4 xv0 = x4[(size_t)(b0 + 0) * 131072 + cb * 1024 + i];
    float4 xv1 = x4[(size_t)(b0 + 1) * 131072 + cb * 1024 + i];
#pragma unroll
    for (int l = 0; l < 16; l++) {
      float4 wv = w4[(size_t)l * 131072 + cb * 1024 + i];
      acc[0][l] += xv0.x * wv.x + xv0.y * wv.y + xv0.z * wv.z + xv0.w * wv.w;
      acc[1][l] += xv1.x * wv.x + xv1.y * wv.y + xv1.z * wv.z + xv1.w * wv.w;
    }
  }
  __shared__ float red[4][32];
#pragma unroll
  for (int bb = 0; bb < 2; bb++)
#pragma unroll
    for (int l = 0; l < 16; l++) {
      float v = acc[bb][l];
#pragma unroll
      for (int off = 1; off < 64; off <<= 1) v += __shfl_xor(v, off);
      if (lane == 0) red[w][bb * 16 + l] = v;
    }
  __syncthreads();
  if (tid < 32) {
    int lb = tid >> 4, l = tid & 15;
    float s = red[0][tid] + red[1][tid] + red[2][tid] + red[3][tid];
    part[(size_t)((b0 + lb) * 16 + l) * 128 + cb] = s;
  }
}

__global__ void k_final2(const float* __restrict__ part, const float* __restrict__ bo,
                         float* __restrict__ out) {
  int idx = threadIdx.x;   // 128 = 8*16
  float s = 0.f;
  for (int c = 0; c < 128; c++) s += part[(size_t)idx * 128 + c];
  s += bo[idx & 15];
  out[idx] = 1.f / (1.f + __expf(-s));
}

extern "C" void kernel_launch(void* const* d_in, const int* in_sizes, int n_in,
                              void* d_out, int out_size, void* d_ws, size_t ws_size,
                              hipStream_t stream) {
  const int*   seqs = (const int*)d_in[0];
  const float* emb  = (const float*)d_in[1];
  const float* Wq   = (const float*)d_in[2];
  const float* bq   = (const float*)d_in[3];
  const float* Wk   = (const float*)d_in[4];
  const float* bk   = (const float*)d_in[5];
  const float* Wv   = (const float*)d_in[6];
  const float* bv   = (const float*)d_in[7];
  const float* Wz   = (const float*)d_in[8];
  const float* bz   = (const float*)d_in[9];
  const float* Wo   = (const float*)d_in[10];
  const float* bo   = (const float*)d_in[11];
  float* out = (float*)d_out;
  float* ws  = (float*)d_ws;

  float* x    = ws;                                    // 4,194,304 f
  u16*   xb   = (u16*)(ws + 4194304);
  u16*   Qf   = (u16*)(ws + 6291456);
  u16*   Kf   = (u16*)(ws + 8388608);
  u16*   Vf   = (u16*)(ws + 10485760);
  u16*   Vt   = (u16*)(ws + 12582912);
  u16*   Zb   = (u16*)(ws + 14680064);
  float* SV   = ws + 16777216;                         // 2,048 f
  u16*   Wqb  = (u16*)(ws + 16787456);
  u16*   Wkb  = (u16*)(ws + 16852992);
  u16*   Wvb  = (u16*)(ws + 16918528);
  u16*   Wzb  = (u16*)(ws + 16984064);
  float* llic = ws + 17049600;                         // 65,536 f (csums then -log2)
  float* part = ws + 6291456;                          // reuses Qf area post-modules

  k_gather<<<(Bb * Ss * 64) / 256, 256, 0, stream>>>(seqs, emb, x, xb);
  k_w2b<<<131072 / 1024, 256, 0, stream>>>(Wq, Wqb);
  k_w2b<<<131072 / 1024, 256, 0, stream>>>(Wk, Wkb);
  k_w2b<<<131072 / 1024, 256, 0, stream>>>(Wv, Wvb);
  k_w2b<<<131072 / 1024, 256, 0, stream>>>(Wz, Wzb);

  for (int m = 0; m < 2; m++) {
    k_qkvm<<<dim3(6, 128), 256, 0, stream>>>(xb, Wqb, Wkb, Wvb, bq, bk, bv, Qf, Kf, Vf, m);
    k_vt<<<dim3(32, 32), 256, 0, stream>>>(Vf, Vt);
    k_vsum<<<dim3(16, 32), 256, 0, stream>>>(Vt, SV, llic);
    k_csum<<<dim3(16, 2, 32), 256, 0, stream>>>(Qf, Kf, llic);
    k_llog<<<256, 256, 0, stream>>>(llic);
    k_att<<<dim3(32, 32), 256, 0, stream>>>(Qf, Kf, Vt, llic, SV, Zb);
    k_zfm<<<dim3(2, 128), 256, 0, stream>>>(Zb, Wzb, bz, x, xb, m);
  }

  k_final1<<<dim3(128, 4), 256, 0, stream>>>(x, Wo, part);
  k_final2<<<1, 128, 0, stream>>>(part, bo, out);
}

// Round 7
// 564.148 us; speedup vs baseline: 1.3003x; 1.3003x over previous
//
#include <hip/hip_runtime.h>
#include <math.h>

#define Bb 8
#define Ss 2048
#define Ee 256
#define Hh 4
#define Dd 64

typedef unsigned short u16;
typedef unsigned int u32;
typedef __attribute__((ext_vector_type(8))) short bf16x8;
typedef __attribute__((ext_vector_type(4))) float f32x4;
typedef __attribute__((ext_vector_type(16))) float f32x16;

__device__ __forceinline__ u16 f2bf(float f) {
  union { float f; u32 u; } c; c.f = f;
  return (u16)((c.u + 0x7FFFu + ((c.u >> 16) & 1u)) >> 16);
}
__device__ __forceinline__ float bf2f(u16 u) {
  union { u32 u; float f; } c; c.u = ((u32)u) << 16;
  return c.f;
}
__device__ __forceinline__ float bf2fs(short s) { return bf2f((u16)s); }
__device__ __forceinline__ float ex2(float x) { return __builtin_amdgcn_exp2f(x); }

// ---------------- weight fp32 -> bf16 convert ----------------
__global__ __launch_bounds__(256) void k_w2b(const float* __restrict__ src,
                                             u16* __restrict__ dst) {
  int idx = (blockIdx.x * 256 + threadIdx.x) * 4;
  float4 v = *reinterpret_cast<const float4*>(src + idx);
  ushort4 o;
  o.x = f2bf(v.x); o.y = f2bf(v.y); o.z = f2bf(v.z); o.w = f2bf(v.w);
  *reinterpret_cast<ushort4*>(dst + idx) = o;
}

// ---------------- embedding gather (fp32 x + bf16 xb) ----------------
__global__ __launch_bounds__(256) void k_gather(const int* __restrict__ seqs,
                                                const float* __restrict__ emb,
                                                float* __restrict__ x,
                                                u16* __restrict__ xb) {
  int idx = blockIdx.x * 256 + threadIdx.x;
  int row = idx >> 6, c4 = idx & 63;
  int tok = seqs[row];
  float4 v = reinterpret_cast<const float4*>(emb)[(size_t)tok * 64 + c4];
  reinterpret_cast<float4*>(x)[(size_t)row * 64 + c4] = v;
  ushort4 o;
  o.x = f2bf(v.x); o.y = f2bf(v.y); o.z = f2bf(v.z); o.w = f2bf(v.w);
  reinterpret_cast<ushort4*>(xb)[(size_t)row * 64 + c4] = o;
}

// ---------------- QKV projection (MFMA bf16): relu(xb@W^T+b) -> bf16 --------
// Q output pre-scaled by log2(e)/16 (folds attention scale AND exp->exp2).
__global__ __launch_bounds__(256) void k_qkvm(const u16* __restrict__ xb,
    const u16* __restrict__ Wqb, const u16* __restrict__ Wkb, const u16* __restrict__ Wvb,
    const float* __restrict__ bq, const float* __restrict__ bk, const float* __restrict__ bv,
    u16* __restrict__ Qf, u16* __restrict__ Kf, u16* __restrict__ Vf, int mod) {
  __shared__ short Xs[128][72];
  __shared__ short Ws[128][72];
  int tid = threadIdx.x;
  int bn = blockIdx.x;
  int arr = bn >> 1, coff = (bn & 1) << 7;
  const u16* W = (arr == 0 ? Wqb : arr == 1 ? Wkb : Wvb) + (size_t)mod * 256 * 256;
  const float* bias = (arr == 0 ? bq : arr == 1 ? bk : bv) + mod * 256;
  u16* Out = (arr == 0 ? Qf : arr == 1 ? Kf : Vf);
  float oscale = (arr == 0) ? 0.0625f * 1.44269504f : 1.0f;
  int s0 = blockIdx.y * 128;
  int lr = tid >> 1, lc = (tid & 1) << 5;
  int w = tid >> 6, lane = tid & 63, ml = lane & 15, q = lane >> 4;
  int sh = (w >> 1) << 6, th = (w & 1) << 6;
  f32x4 acc[4][4] = {};
  for (int k0 = 0; k0 < 256; k0 += 64) {
#pragma unroll
    for (int hh = 0; hh < 4; hh++) {
      *reinterpret_cast<bf16x8*>(&Xs[lr][lc + hh * 8]) =
          *reinterpret_cast<const bf16x8*>(xb + (size_t)(s0 + lr) * Ee + k0 + lc + hh * 8);
      *reinterpret_cast<bf16x8*>(&Ws[lr][lc + hh * 8]) =
          *reinterpret_cast<const bf16x8*>(W + (size_t)(coff + lr) * Ee + k0 + lc + hh * 8);
    }
    __syncthreads();
#pragma unroll
    for (int ks = 0; ks < 2; ks++) {
      bf16x8 af[4], bfr[4];
#pragma unroll
      for (int mt = 0; mt < 4; mt++)
        af[mt] = *reinterpret_cast<const bf16x8*>(&Xs[sh + mt * 16 + ml][ks * 32 + q * 8]);
#pragma unroll
      for (int nt = 0; nt < 4; nt++)
        bfr[nt] = *reinterpret_cast<const bf16x8*>(&Ws[th + nt * 16 + ml][ks * 32 + q * 8]);
#pragma unroll
      for (int mt = 0; mt < 4; mt++)
#pragma unroll
        for (int nt = 0; nt < 4; nt++)
          acc[mt][nt] = __builtin_amdgcn_mfma_f32_16x16x32_bf16(af[mt], bfr[nt], acc[mt][nt], 0, 0, 0);
    }
    __syncthreads();
  }
#pragma unroll
  for (int mt = 0; mt < 4; mt++)
#pragma unroll
    for (int nt = 0; nt < 4; nt++)
#pragma unroll
      for (int r = 0; r < 4; r++) {
        int gm = s0 + sh + mt * 16 + q * 4 + r;
        int cc = coff + th + nt * 16 + ml;
        float v = acc[mt][nt][r] + bias[cc];
        v = (v > 0.f ? v : 0.f) * oscale;
        Out[(size_t)gm * Ee + cc] = f2bf(v);
      }
}

// ---------------- V transpose: Vf[b][t][h*64+d] -> Vt[(b*4+h)*64+d][t] -------
__global__ __launch_bounds__(256) void k_vt(const u16* __restrict__ Vf,
                                            u16* __restrict__ Vt) {
  __shared__ u16 T[64][72];
  int tid = threadIdx.x;
  int t0 = blockIdx.x * 64;
  int z = blockIdx.y;
  int b = z >> 2, h = z & 3;
  int lr = tid >> 2, lc = (tid & 3) << 4;
#pragma unroll
  for (int hh = 0; hh < 2; hh++) {
    bf16x8 v = *reinterpret_cast<const bf16x8*>(
        Vf + (size_t)(b * Ss + t0 + lr) * Ee + h * Dd + lc + hh * 8);
#pragma unroll
    for (int j = 0; j < 8; j++) T[lr][lc + hh * 8 + j] = (u16)v[j];
  }
  __syncthreads();
#pragma unroll
  for (int j = 0; j < 16; j++) {
    Vt[((size_t)z * Dd + lr) * Ss + t0 + lc + j] = T[lc + j][lr];
  }
}

// ---------------- SV[z][d] = sum_t Vt[z*64+d][t]; also zero csums ------------
__global__ __launch_bounds__(256) void k_vsum(const u16* __restrict__ Vt,
                                              float* __restrict__ SV,
                                              float* __restrict__ csums) {
  int gi = (blockIdx.y * gridDim.x + blockIdx.x) * 256 + threadIdx.x;
  if (gi < 32 * Ss) csums[gi] = 0.f;
  int z = blockIdx.y;
  int d = blockIdx.x * 4 + (threadIdx.x >> 6);
  int lane = threadIdx.x & 63;
  const u16* row = Vt + ((size_t)z * Dd + d) * Ss;
  float s = 0.f;
#pragma unroll
  for (int it = 0; it < 4; it++) {
    bf16x8 v = *reinterpret_cast<const bf16x8*>(row + it * 512 + lane * 8);
#pragma unroll
    for (int j = 0; j < 8; j++) s += bf2fs(v[j]);
  }
#pragma unroll
  for (int off = 32; off; off >>= 1) s += __shfl_xor(s, off);
  if (lane == 0) SV[(size_t)z * Dd + d] = s;
}

// ---------------- pass 1: csums[t] += sum_s exp2(S) (barrier-free loop) ------
__global__ __launch_bounds__(256, 4) void k_csum(const u16* __restrict__ Qf,
    const u16* __restrict__ Kf, float* __restrict__ csums) {
  __shared__ float csm[2][128];
  int tid = threadIdx.x;
  int lin = (blockIdx.z * 2 + blockIdx.y) * 16 + blockIdx.x;
  int wgid = (lin & 7) * 128 + (lin >> 3);   // XCD-chunked, bijective (1024 % 8 == 0)
  int ttile = wgid & 15, shalf = (wgid >> 4) & 1, z = wgid >> 5;
  int b = z >> 2, h = z & 3;
  const u16* Qb = Qf + (size_t)b * Ss * Ee + h * Dd;
  const u16* Kb = Kf + (size_t)b * Ss * Ee + h * Dd;
  int w = tid >> 6, lane = tid & 63, l31 = lane & 31, hi = lane >> 5;
  int sh = (w >> 1) << 6, th = (w & 1) << 6;
  const u16* kr = Kb + (size_t)(ttile * 128 + th + l31) * Ee + hi * 8;
  bf16x8 kb[2][4];
#pragma unroll
  for (int tt = 0; tt < 2; tt++)
#pragma unroll
    for (int kk = 0; kk < 4; kk++)
      kb[tt][kk] = *reinterpret_cast<const bf16x8*>(kr + (size_t)tt * 32 * Ee + kk * 16);
  const u16* Qr0 = Qb + (size_t)(shalf * 1024 + sh + l31) * Ee + hi * 8;
  bf16x8 qc0 = *reinterpret_cast<const bf16x8*>(Qr0);
  bf16x8 qc1 = *reinterpret_cast<const bf16x8*>(Qr0 + 16);
  bf16x8 qc2 = *reinterpret_cast<const bf16x8*>(Qr0 + 32);
  bf16x8 qc3 = *reinterpret_cast<const bf16x8*>(Qr0 + 48);
  float cs0 = 0.f, cs1 = 0.f;
  for (int it = 0; it < 16; it++) {
    int itn = (it + 1) & 15;
    const u16* qnp = Qr0 + (size_t)(((itn >> 1) << 7) + ((itn & 1) << 5)) * Ee;
    bf16x8 qn0 = *reinterpret_cast<const bf16x8*>(qnp);
    bf16x8 qn1 = *reinterpret_cast<const bf16x8*>(qnp + 16);
    bf16x8 qn2 = *reinterpret_cast<const bf16x8*>(qnp + 32);
    bf16x8 qn3 = *reinterpret_cast<const bf16x8*>(qnp + 48);
    f32x16 a0 = {}, a1 = {};
    __builtin_amdgcn_s_setprio(1);
    a0 = __builtin_amdgcn_mfma_f32_32x32x16_bf16(qc0, kb[0][0], a0, 0, 0, 0);
    a1 = __builtin_amdgcn_mfma_f32_32x32x16_bf16(qc0, kb[1][0], a1, 0, 0, 0);
    a0 = __builtin_amdgcn_mfma_f32_32x32x16_bf16(qc1, kb[0][1], a0, 0, 0, 0);
    a1 = __builtin_amdgcn_mfma_f32_32x32x16_bf16(qc1, kb[1][1], a1, 0, 0, 0);
    a0 = __builtin_amdgcn_mfma_f32_32x32x16_bf16(qc2, kb[0][2], a0, 0, 0, 0);
    a1 = __builtin_amdgcn_mfma_f32_32x32x16_bf16(qc2, kb[1][2], a1, 0, 0, 0);
    a0 = __builtin_amdgcn_mfma_f32_32x32x16_bf16(qc3, kb[0][3], a0, 0, 0, 0);
    a1 = __builtin_amdgcn_mfma_f32_32x32x16_bf16(qc3, kb[1][3], a1, 0, 0, 0);
    __builtin_amdgcn_s_setprio(0);
#pragma unroll
    for (int j = 0; j < 16; j++) { cs0 += ex2(a0[j]); cs1 += ex2(a1[j]); }
    qc0 = qn0; qc1 = qn1; qc2 = qn2; qc3 = qn3;
  }
  cs0 += __shfl_xor(cs0, 32);
  cs1 += __shfl_xor(cs1, 32);
  if (lane < 32) {
    csm[w >> 1][th + l31] = cs0;
    csm[w >> 1][th + 32 + l31] = cs1;
  }
  __syncthreads();
  if (tid < 128)
    atomicAdd(&csums[(size_t)z * Ss + ttile * 128 + tid], csm[0][tid] + csm[1][tid]);
}

// ---------------- csums -> llic = -log2(csums), in place ---------------------
__global__ void k_llog(float* __restrict__ llic) {
  int i = blockIdx.x * 256 + threadIdx.x;
  llic[i] = -__log2f(llic[i]);
}

// ---------------- pass 2: fused attention (r0 structure, 64-row s-tiles) -----
// grid (32 s-tiles, 32 z). Per 64-t chunk: stage K,V coalesced to LDS ->
// QK-MFMA (16x16, Q A-frags in regs) -> e1=exp2(S+llic) -> A2'=expm1-poly4
// -> A2s LDS -> PV-MFMA. Halved s-tile vs r0 doubles grid to 1024 blocks
// (r0's occupancy was grid-capped at 2 blocks/CU); LDS 28.7 KB, VGPR ~90
// -> 4-5 blocks/CU. O = (SV + A2'@V) / (2048 + rowsum(A2')) -> bf16 Zb.
__global__ __launch_bounds__(256) void k_att(const u16* __restrict__ Qf,
    const u16* __restrict__ Kf, const u16* __restrict__ Vt,
    const float* __restrict__ llic, const float* __restrict__ SV,
    u16* __restrict__ Zb) {
  __shared__ short Ks[64 * 72];      // 9.2 KB
  __shared__ short Vs[64 * 72];      // 9.2 KB
  __shared__ short A2s[64 * 76];     // 9.7 KB
  __shared__ float rs_s[2][64];
  int tid = threadIdx.x;
  int lin = blockIdx.y * 32 + blockIdx.x;
  int wgid = (lin & 7) * 128 + (lin >> 3);   // XCD-chunked, bijective
  int z = wgid >> 5, sblk = wgid & 31;
  int b = z >> 2, h = z & 3;
  const u16* Qb = Qf + (size_t)b * Ss * Ee + h * Dd;
  const u16* Kb = Kf + (size_t)b * Ss * Ee + h * Dd;
  const u16* VtZ = Vt + (size_t)z * Dd * Ss;
  const float* lz = llic + (size_t)z * Ss;
  int s0 = sblk * 64;
  int w = tid >> 6, lane = tid & 63, ml = lane & 15, q = lane >> 4;
  int wsd = (w >> 1) << 5, wt = (w & 1) << 5;
  // preload Q A-frags (loop-invariant, 16 VGPRs)
  bf16x8 qa[2][2];
#pragma unroll
  for (int ks = 0; ks < 2; ks++)
#pragma unroll
    for (int mt = 0; mt < 2; mt++)
      qa[ks][mt] = *reinterpret_cast<const bf16x8*>(
          Qb + (size_t)(s0 + wsd + mt * 16 + ml) * Ee + ks * 32 + q * 8);
  f32x4 acc2[4] = {};
  f32x4 rsv[2] = {};
  for (int t0 = 0; t0 < Ss; t0 += 64) {
    __syncthreads();
    if (tid < 128) {
      int r2 = tid >> 1, h2 = (tid & 1) << 5;
#pragma unroll
      for (int j = 0; j < 4; j++)
        *reinterpret_cast<bf16x8*>(&Ks[r2 * 72 + h2 + j * 8]) =
            *reinterpret_cast<const bf16x8*>(Kb + (size_t)(t0 + r2) * Ee + h2 + j * 8);
    } else {
      int t2 = tid - 128;
      int r2 = t2 >> 1, h2 = (t2 & 1) << 5;
#pragma unroll
      for (int j = 0; j < 4; j++)
        *reinterpret_cast<bf16x8*>(&Vs[r2 * 72 + h2 + j * 8]) =
            *reinterpret_cast<const bf16x8*>(VtZ + (size_t)r2 * Ss + t0 + h2 + j * 8);
    }
    __syncthreads();
    // QK: wave computes 32 s-rows x 32 t-cols
    f32x4 acc[2][2] = {};
#pragma unroll
    for (int ks = 0; ks < 2; ks++) {
      bf16x8 bf[2];
#pragma unroll
      for (int nt = 0; nt < 2; nt++)
        bf[nt] = *reinterpret_cast<const bf16x8*>(&Ks[(wt + nt * 16 + ml) * 72 + ks * 32 + q * 8]);
#pragma unroll
      for (int mt = 0; mt < 2; mt++)
#pragma unroll
        for (int nt = 0; nt < 2; nt++)
          acc[mt][nt] = __builtin_amdgcn_mfma_f32_16x16x32_bf16(qa[ks][mt], bf[nt], acc[mt][nt], 0, 0, 0);
    }
    // transform: e1 = exp2(S + llic) in (0,1]; A2' = expm1(e1) poly4
#pragma unroll
    for (int nt = 0; nt < 2; nt++) {
      float lcv = lz[t0 + wt + nt * 16 + ml];
#pragma unroll
      for (int mt = 0; mt < 2; mt++)
#pragma unroll
        for (int r = 0; r < 4; r++) {
          float e1 = ex2(acc[mt][nt][r] + lcv);
          float p = e1 * (1.f + e1 * (0.5f + e1 * (0.166666667f + e1 * 0.0416666667f)));
          rsv[mt][r] += p;
          union { float f; u32 u; } cv; cv.f = p;
          A2s[(wsd + mt * 16 + q * 4 + r) * 76 + wt + nt * 16 + ml] =
              (short)((cv.u + 0x8000u) >> 16);
        }
    }
    __syncthreads();
    // PV: wave owns 16 s-rows x 64 d
#pragma unroll
    for (int ks = 0; ks < 2; ks++) {
      bf16x8 af2 = *reinterpret_cast<const bf16x8*>(&A2s[(w * 16 + ml) * 76 + ks * 32 + q * 8]);
      bf16x8 bv[4];
#pragma unroll
      for (int nt = 0; nt < 4; nt++)
        bv[nt] = *reinterpret_cast<const bf16x8*>(&Vs[(nt * 16 + ml) * 72 + ks * 32 + q * 8]);
#pragma unroll
      for (int nt = 0; nt < 4; nt++)
        acc2[nt] = __builtin_amdgcn_mfma_f32_16x16x32_bf16(af2, bv[nt], acc2[nt], 0, 0, 0);
    }
  }
  // row sums across the 16 col-lanes
#pragma unroll
  for (int mt = 0; mt < 2; mt++)
#pragma unroll
    for (int r = 0; r < 4; r++) {
      float v = rsv[mt][r];
      v += __shfl_xor(v, 1); v += __shfl_xor(v, 2);
      v += __shfl_xor(v, 4); v += __shfl_xor(v, 8);
      if (ml == 0) rs_s[w & 1][wsd + mt * 16 + q * 4 + r] = v;
    }
  __syncthreads();
  const float* SVz = SV + (size_t)z * Dd;
#pragma unroll
  for (int r = 0; r < 4; r++) {
    int row = w * 16 + q * 4 + r;
    float inv = 1.f / (2048.f + rs_s[0][row] + rs_s[1][row]);
#pragma unroll
    for (int nt = 0; nt < 4; nt++) {
      float o = (SVz[nt * 16 + ml] + acc2[nt][r]) * inv;
      Zb[(size_t)(b * Ss + s0 + row) * Ee + h * Dd + nt * 16 + ml] = f2bf(o);
    }
  }
}

// ---------------- ZF (MFMA bf16) + residual: x += Zb@Wz^T + bz; xb refresh ---
__global__ __launch_bounds__(256) void k_zfm(const u16* __restrict__ Zb,
    const u16* __restrict__ Wzb, const float* __restrict__ bzp,
    float* __restrict__ x, u16* __restrict__ xb, int mod) {
  __shared__ short Zs[128][72];
  __shared__ short Ws[128][72];
  int tid = threadIdx.x;
  int coff = blockIdx.x << 7;
  const u16* W = Wzb + (size_t)mod * 256 * 256;
  const float* bias = bzp + mod * Ee;
  int s0 = blockIdx.y * 128;
  int lr = tid >> 1, lc = (tid & 1) << 5;
  int w = tid >> 6, lane = tid & 63, ml = lane & 15, q = lane >> 4;
  int sh = (w >> 1) << 6, th = (w & 1) << 6;
  f32x4 acc[4][4] = {};
  for (int k0 = 0; k0 < 256; k0 += 64) {
#pragma unroll
    for (int hh = 0; hh < 4; hh++) {
      *reinterpret_cast<bf16x8*>(&Zs[lr][lc + hh * 8]) =
          *reinterpret_cast<const bf16x8*>(Zb + (size_t)(s0 + lr) * Ee + k0 + lc + hh * 8);
      *reinterpret_cast<bf16x8*>(&Ws[lr][lc + hh * 8]) =
          *reinterpret_cast<const bf16x8*>(W + (size_t)(coff + lr) * Ee + k0 + lc + hh * 8);
    }
    __syncthreads();
#pragma unroll
    for (int ks = 0; ks < 2; ks++) {
      bf16x8 af[4], bfr[4];
#pragma unroll
      for (int mt = 0; mt < 4; mt++)
        af[mt] = *reinterpret_cast<const bf16x8*>(&Zs[sh + mt * 16 + ml][ks * 32 + q * 8]);
#pragma unroll
      for (int nt = 0; nt < 4; nt++)
        bfr[nt] = *reinterpret_cast<const bf16x8*>(&Ws[th + nt * 16 + ml][ks * 32 + q * 8]);
#pragma unroll
      for (int mt = 0; mt < 4; mt++)
#pragma unroll
        for (int nt = 0; nt < 4; nt++)
          acc[mt][nt] = __builtin_amdgcn_mfma_f32_16x16x32_bf16(af[mt], bfr[nt], acc[mt][nt], 0, 0, 0);
    }
    __syncthreads();
  }
#pragma unroll
  for (int mt = 0; mt < 4; mt++)
#pragma unroll
    for (int nt = 0; nt < 4; nt++)
#pragma unroll
      for (int r = 0; r < 4; r++) {
        int gm = s0 + sh + mt * 16 + q * 4 + r;
        int gn = coff + th + nt * 16 + ml;
        float xv = x[(size_t)gm * Ee + gn] + acc[mt][nt][r] + bias[gn];
        x[(size_t)gm * Ee + gn] = xv;
        xb[(size_t)gm * Ee + gn] = f2bf(xv);
      }
}

// ---------------- final head: block = (c-chunk of 4096, 2 batches) -----------
__global__ __launch_bounds__(256) void k_final1(const float* __restrict__ x,
    const float* __restrict__ Wo, float* __restrict__ part) {
  int cb = blockIdx.x;                 // 0..127 chunk of 4096 floats
  int b0 = blockIdx.y * 2;             // 0,2,4,6
  int tid = threadIdx.x;
  int w = tid >> 6, lane = tid & 63;
  float acc[2][16];
#pragma unroll
  for (int bb = 0; bb < 2; bb++)
#pragma unroll
    for (int l = 0; l < 16; l++) acc[bb][l] = 0.f;
  const float4* x4 = reinterpret_cast<const float4*>(x);
  const float4* w4 = reinterpret_cast<const float4*>(Wo);
#pragma unroll
  for (int it = 0; it < 4; it++) {
    int i = it * 256 + tid;
    float4 xv0 = x4[(size_t)(b0 + 0) * 131072 + cb * 1024 + i];
    float4 xv1 = x4[(size_t)(b0 + 1) * 131072 + cb * 1024 + i];
#pragma unroll
    for (int l = 0; l < 16; l++) {
      float4 wv = w4[(size_t)l * 131072 + cb * 1024 + i];
      acc[0][l] += xv0.x * wv.x + xv0.y * wv.y + xv0.z * wv.z + xv0.w * wv.w;
      acc[1][l] += xv1.x * wv.x + xv1.y * wv.y + xv1.z * wv.z + xv1.w * wv.w;
    }
  }
  __shared__ float red[4][32];
#pragma unroll
  for (int bb = 0; bb < 2; bb++)
#pragma unroll
    for (int l = 0; l < 16; l++) {
      float v = acc[bb][l];
#pragma unroll
      for (int off = 1; off < 64; off <<= 1) v += __shfl_xor(v, off);
      if (lane == 0) red[w][bb * 16 + l] = v;
    }
  __syncthreads();
  if (tid < 32) {
    int lb = tid >> 4, l = tid & 15;
    float s = red[0][tid] + red[1][tid] + red[2][tid] + red[3][tid];
    part[(size_t)((b0 + lb) * 16 + l) * 128 + cb] = s;
  }
}

__global__ void k_final2(const float* __restrict__ part, const float* __restrict__ bo,
                         float* __restrict__ out) {
  int idx = threadIdx.x;   // 128 = 8*16
  float s = 0.f;
  for (int c = 0; c < 128; c++) s += part[(size_t)idx * 128 + c];
  s += bo[idx & 15];
  out[idx] = 1.f / (1.f + __expf(-s));
}

extern "C" void kernel_launch(void* const* d_in, const int* in_sizes, int n_in,
                              void* d_out, int out_size, void* d_ws, size_t ws_size,
                              hipStream_t stream) {
  const int*   seqs = (const int*)d_in[0];
  const float* emb  = (const float*)d_in[1];
  const float* Wq   = (const float*)d_in[2];
  const float* bq   = (const float*)d_in[3];
  const float* Wk   = (const float*)d_in[4];
  const float* bk   = (const float*)d_in[5];
  const float* Wv   = (const float*)d_in[6];
  const float* bv   = (const float*)d_in[7];
  const float* Wz   = (const float*)d_in[8];
  const float* bz   = (const float*)d_in[9];
  const float* Wo   = (const float*)d_in[10];
  const float* bo   = (const float*)d_in[11];
  float* out = (float*)d_out;
  float* ws  = (float*)d_ws;

  float* x    = ws;                                    // 4,194,304 f
  u16*   xb   = (u16*)(ws + 4194304);
  u16*   Qf   = (u16*)(ws + 6291456);
  u16*   Kf   = (u16*)(ws + 8388608);
  u16*   Vf   = (u16*)(ws + 10485760);
  u16*   Vt   = (u16*)(ws + 12582912);
  u16*   Zb   = (u16*)(ws + 14680064);
  float* SV   = ws + 16777216;                         // 2,048 f
  u16*   Wqb  = (u16*)(ws + 16787456);
  u16*   Wkb  = (u16*)(ws + 16852992);
  u16*   Wvb  = (u16*)(ws + 16918528);
  u16*   Wzb  = (u16*)(ws + 16984064);
  float* llic = ws + 17049600;                         // 65,536 f (csums then -log2)
  float* part = ws + 6291456;                          // reuses Qf area post-modules

  k_gather<<<(Bb * Ss * 64) / 256, 256, 0, stream>>>(seqs, emb, x, xb);
  k_w2b<<<131072 / 1024, 256, 0, stream>>>(Wq, Wqb);
  k_w2b<<<131072 / 1024, 256, 0, stream>>>(Wk, Wkb);
  k_w2b<<<131072 / 1024, 256, 0, stream>>>(Wv, Wvb);
  k_w2b<<<131072 / 1024, 256, 0, stream>>>(Wz, Wzb);

  for (int m = 0; m < 2; m++) {
    k_qkvm<<<dim3(6, 128), 256, 0, stream>>>(xb, Wqb, Wkb, Wvb, bq, bk, bv, Qf, Kf, Vf, m);
    k_vt<<<dim3(32, 32), 256, 0, stream>>>(Vf, Vt);
    k_vsum<<<dim3(16, 32), 256, 0, stream>>>(Vt, SV, llic);
    k_csum<<<dim3(16, 2, 32), 256, 0, stream>>>(Qf, Kf, llic);
    k_llog<<<256, 256, 0, stream>>>(llic);
    k_att<<<dim3(32, 32), 256, 0, stream>>>(Qf, Kf, Vt, llic, SV, Zb);
    k_zfm<<<dim3(2, 128), 256, 0, stream>>>(Zb, Wzb, bz, x, xb, m);
  }

  k_final1<<<dim3(128, 4), 256, 0, stream>>>(x, Wo, part);
  k_final2<<<1, 128, 0, stream>>>(part, bo, out);
}

// Round 8
// 506.306 us; speedup vs baseline: 1.4488x; 1.1142x over previous
//
#include <hip/hip_runtime.h>
#include <math.h>

#define Bb 8
#define Ss 2048
#define Ee 256
#define Hh 4
#define Dd 64

typedef unsigned short u16;
typedef unsigned int u32;
typedef __attribute__((ext_vector_type(8))) short bf16x8;
typedef __attribute__((ext_vector_type(4))) float f32x4;
typedef __attribute__((ext_vector_type(16))) float f32x16;

__device__ __forceinline__ u16 f2bf(float f) {
  union { float f; u32 u; } c; c.f = f;
  return (u16)((c.u + 0x7FFFu + ((c.u >> 16) & 1u)) >> 16);
}
__device__ __forceinline__ float bf2f(u16 u) {
  union { u32 u; float f; } c; c.u = ((u32)u) << 16;
  return c.f;
}
__device__ __forceinline__ float bf2fs(short s) { return bf2f((u16)s); }
__device__ __forceinline__ float ex2(float x) { return __builtin_amdgcn_exp2f(x); }

// ---------------- weight fp32 -> bf16 convert ----------------
__global__ __launch_bounds__(256) void k_w2b(const float* __restrict__ src,
                                             u16* __restrict__ dst) {
  int idx = (blockIdx.x * 256 + threadIdx.x) * 4;
  float4 v = *reinterpret_cast<const float4*>(src + idx);
  ushort4 o;
  o.x = f2bf(v.x); o.y = f2bf(v.y); o.z = f2bf(v.z); o.w = f2bf(v.w);
  *reinterpret_cast<ushort4*>(dst + idx) = o;
}

// ---------------- embedding gather (fp32 x + bf16 xb) ----------------
__global__ __launch_bounds__(256) void k_gather(const int* __restrict__ seqs,
                                                const float* __restrict__ emb,
                                                float* __restrict__ x,
                                                u16* __restrict__ xb) {
  int idx = blockIdx.x * 256 + threadIdx.x;
  int row = idx >> 6, c4 = idx & 63;
  int tok = seqs[row];
  float4 v = reinterpret_cast<const float4*>(emb)[(size_t)tok * 64 + c4];
  reinterpret_cast<float4*>(x)[(size_t)row * 64 + c4] = v;
  ushort4 o;
  o.x = f2bf(v.x); o.y = f2bf(v.y); o.z = f2bf(v.z); o.w = f2bf(v.w);
  reinterpret_cast<ushort4*>(xb)[(size_t)row * 64 + c4] = o;
}

// ---------------- QKV projection (MFMA bf16): relu(xb@W^T+b) -> bf16 --------
// Q output pre-scaled by log2(e)/16 (folds attention scale AND exp->exp2).
__global__ __launch_bounds__(256) void k_qkvm(const u16* __restrict__ xb,
    const u16* __restrict__ Wqb, const u16* __restrict__ Wkb, const u16* __restrict__ Wvb,
    const float* __restrict__ bq, const float* __restrict__ bk, const float* __restrict__ bv,
    u16* __restrict__ Qf, u16* __restrict__ Kf, u16* __restrict__ Vf, int mod) {
  __shared__ short Xs[128][72];
  __shared__ short Ws[128][72];
  int tid = threadIdx.x;
  int bn = blockIdx.x;
  int arr = bn >> 1, coff = (bn & 1) << 7;
  const u16* W = (arr == 0 ? Wqb : arr == 1 ? Wkb : Wvb) + (size_t)mod * 256 * 256;
  const float* bias = (arr == 0 ? bq : arr == 1 ? bk : bv) + mod * 256;
  u16* Out = (arr == 0 ? Qf : arr == 1 ? Kf : Vf);
  float oscale = (arr == 0) ? 0.0625f * 1.44269504f : 1.0f;
  int s0 = blockIdx.y * 128;
  int lr = tid >> 1, lc = (tid & 1) << 5;
  int w = tid >> 6, lane = tid & 63, ml = lane & 15, q = lane >> 4;
  int sh = (w >> 1) << 6, th = (w & 1) << 6;
  f32x4 acc[4][4] = {};
  for (int k0 = 0; k0 < 256; k0 += 64) {
#pragma unroll
    for (int hh = 0; hh < 4; hh++) {
      *reinterpret_cast<bf16x8*>(&Xs[lr][lc + hh * 8]) =
          *reinterpret_cast<const bf16x8*>(xb + (size_t)(s0 + lr) * Ee + k0 + lc + hh * 8);
      *reinterpret_cast<bf16x8*>(&Ws[lr][lc + hh * 8]) =
          *reinterpret_cast<const bf16x8*>(W + (size_t)(coff + lr) * Ee + k0 + lc + hh * 8);
    }
    __syncthreads();
#pragma unroll
    for (int ks = 0; ks < 2; ks++) {
      bf16x8 af[4], bfr[4];
#pragma unroll
      for (int mt = 0; mt < 4; mt++)
        af[mt] = *reinterpret_cast<const bf16x8*>(&Xs[sh + mt * 16 + ml][ks * 32 + q * 8]);
#pragma unroll
      for (int nt = 0; nt < 4; nt++)
        bfr[nt] = *reinterpret_cast<const bf16x8*>(&Ws[th + nt * 16 + ml][ks * 32 + q * 8]);
#pragma unroll
      for (int mt = 0; mt < 4; mt++)
#pragma unroll
        for (int nt = 0; nt < 4; nt++)
          acc[mt][nt] = __builtin_amdgcn_mfma_f32_16x16x32_bf16(af[mt], bfr[nt], acc[mt][nt], 0, 0, 0);
    }
    __syncthreads();
  }
#pragma unroll
  for (int mt = 0; mt < 4; mt++)
#pragma unroll
    for (int nt = 0; nt < 4; nt++)
#pragma unroll
      for (int r = 0; r < 4; r++) {
        int gm = s0 + sh + mt * 16 + q * 4 + r;
        int cc = coff + th + nt * 16 + ml;
        float v = acc[mt][nt][r] + bias[cc];
        v = (v > 0.f ? v : 0.f) * oscale;
        Out[(size_t)gm * Ee + cc] = f2bf(v);
      }
}

// ---------------- V transpose: Vf[b][t][h*64+d] -> Vt[(b*4+h)*64+d][t] -------
__global__ __launch_bounds__(256) void k_vt(const u16* __restrict__ Vf,
                                            u16* __restrict__ Vt) {
  __shared__ u16 T[64][72];
  int tid = threadIdx.x;
  int t0 = blockIdx.x * 64;
  int z = blockIdx.y;
  int b = z >> 2, h = z & 3;
  int lr = tid >> 2, lc = (tid & 3) << 4;
#pragma unroll
  for (int hh = 0; hh < 2; hh++) {
    bf16x8 v = *reinterpret_cast<const bf16x8*>(
        Vf + (size_t)(b * Ss + t0 + lr) * Ee + h * Dd + lc + hh * 8);
#pragma unroll
    for (int j = 0; j < 8; j++) T[lr][lc + hh * 8 + j] = (u16)v[j];
  }
  __syncthreads();
#pragma unroll
  for (int j = 0; j < 16; j++) {
    Vt[((size_t)z * Dd + lr) * Ss + t0 + lc + j] = T[lc + j][lr];
  }
}

// ---------------- SV[z][d] = sum_t Vt[z*64+d][t]; also zero csums ------------
__global__ __launch_bounds__(256) void k_vsum(const u16* __restrict__ Vt,
                                              float* __restrict__ SV,
                                              float* __restrict__ csums) {
  int gi = (blockIdx.y * gridDim.x + blockIdx.x) * 256 + threadIdx.x;
  if (gi < 32 * Ss) csums[gi] = 0.f;
  int z = blockIdx.y;
  int d = blockIdx.x * 4 + (threadIdx.x >> 6);
  int lane = threadIdx.x & 63;
  const u16* row = Vt + ((size_t)z * Dd + d) * Ss;
  float s = 0.f;
#pragma unroll
  for (int it = 0; it < 4; it++) {
    bf16x8 v = *reinterpret_cast<const bf16x8*>(row + it * 512 + lane * 8);
#pragma unroll
    for (int j = 0; j < 8; j++) s += bf2fs(v[j]);
  }
#pragma unroll
  for (int off = 32; off; off >>= 1) s += __shfl_xor(s, off);
  if (lane == 0) SV[(size_t)z * Dd + d] = s;
}

// ---------------- pass 1: csums[t] += sum_s exp2(S) (barrier-free loop) ------
__global__ __launch_bounds__(256, 4) void k_csum(const u16* __restrict__ Qf,
    const u16* __restrict__ Kf, float* __restrict__ csums) {
  __shared__ float csm[2][128];
  int tid = threadIdx.x;
  int lin = (blockIdx.z * 2 + blockIdx.y) * 16 + blockIdx.x;
  int wgid = (lin & 7) * 128 + (lin >> 3);   // XCD-chunked, bijective (1024 % 8 == 0)
  int ttile = wgid & 15, shalf = (wgid >> 4) & 1, z = wgid >> 5;
  int b = z >> 2, h = z & 3;
  const u16* Qb = Qf + (size_t)b * Ss * Ee + h * Dd;
  const u16* Kb = Kf + (size_t)b * Ss * Ee + h * Dd;
  int w = tid >> 6, lane = tid & 63, l31 = lane & 31, hi = lane >> 5;
  int sh = (w >> 1) << 6, th = (w & 1) << 6;
  const u16* kr = Kb + (size_t)(ttile * 128 + th + l31) * Ee + hi * 8;
  bf16x8 kb[2][4];
#pragma unroll
  for (int tt = 0; tt < 2; tt++)
#pragma unroll
    for (int kk = 0; kk < 4; kk++)
      kb[tt][kk] = *reinterpret_cast<const bf16x8*>(kr + (size_t)tt * 32 * Ee + kk * 16);
  const u16* Qr0 = Qb + (size_t)(shalf * 1024 + sh + l31) * Ee + hi * 8;
  bf16x8 qc0 = *reinterpret_cast<const bf16x8*>(Qr0);
  bf16x8 qc1 = *reinterpret_cast<const bf16x8*>(Qr0 + 16);
  bf16x8 qc2 = *reinterpret_cast<const bf16x8*>(Qr0 + 32);
  bf16x8 qc3 = *reinterpret_cast<const bf16x8*>(Qr0 + 48);
  float cs0 = 0.f, cs1 = 0.f;
  for (int it = 0; it < 16; it++) {
    int itn = (it + 1) & 15;
    const u16* qnp = Qr0 + (size_t)(((itn >> 1) << 7) + ((itn & 1) << 5)) * Ee;
    bf16x8 qn0 = *reinterpret_cast<const bf16x8*>(qnp);
    bf16x8 qn1 = *reinterpret_cast<const bf16x8*>(qnp + 16);
    bf16x8 qn2 = *reinterpret_cast<const bf16x8*>(qnp + 32);
    bf16x8 qn3 = *reinterpret_cast<const bf16x8*>(qnp + 48);
    f32x16 a0 = {}, a1 = {};
    __builtin_amdgcn_s_setprio(1);
    a0 = __builtin_amdgcn_mfma_f32_32x32x16_bf16(qc0, kb[0][0], a0, 0, 0, 0);
    a1 = __builtin_amdgcn_mfma_f32_32x32x16_bf16(qc0, kb[1][0], a1, 0, 0, 0);
    a0 = __builtin_amdgcn_mfma_f32_32x32x16_bf16(qc1, kb[0][1], a0, 0, 0, 0);
    a1 = __builtin_amdgcn_mfma_f32_32x32x16_bf16(qc1, kb[1][1], a1, 0, 0, 0);
    a0 = __builtin_amdgcn_mfma_f32_32x32x16_bf16(qc2, kb[0][2], a0, 0, 0, 0);
    a1 = __builtin_amdgcn_mfma_f32_32x32x16_bf16(qc2, kb[1][2], a1, 0, 0, 0);
    a0 = __builtin_amdgcn_mfma_f32_32x32x16_bf16(qc3, kb[0][3], a0, 0, 0, 0);
    a1 = __builtin_amdgcn_mfma_f32_32x32x16_bf16(qc3, kb[1][3], a1, 0, 0, 0);
    __builtin_amdgcn_s_setprio(0);
#pragma unroll
    for (int j = 0; j < 16; j++) { cs0 += ex2(a0[j]); cs1 += ex2(a1[j]); }
    qc0 = qn0; qc1 = qn1; qc2 = qn2; qc3 = qn3;
  }
  cs0 += __shfl_xor(cs0, 32);
  cs1 += __shfl_xor(cs1, 32);
  if (lane < 32) {
    csm[w >> 1][th + l31] = cs0;
    csm[w >> 1][th + 32 + l31] = cs1;
  }
  __syncthreads();
  if (tid < 128)
    atomicAdd(&csums[(size_t)z * Ss + ttile * 128 + tid], csm[0][tid] + csm[1][tid]);
}

// ---------------- csums -> llic = -log2(csums), in place ---------------------
__global__ void k_llog(float* __restrict__ llic) {
  int i = blockIdx.x * 256 + threadIdx.x;
  llic[i] = -__log2f(llic[i]);
}

// ---------------- pass 2: fused attention (r0 tiling, 8 waves/block) ---------
// grid (16 s-tiles of 128 rows, 32 z), 512 threads. Same 128-row tile, same
// staging traffic, same A2s scheme as the 94us r0 kernel -- but the per-chunk
// work is split across 8 waves instead of 4, so 2 blocks/CU = 16 waves/CU
// (r0 was grid-capped at 8). QK: wave (sq,tq) does 32 s x 32 t. PV: wave w
// does 16 s x 64 d. llic in exp2 domain.
__global__ __launch_bounds__(512, 4) void k_att(const u16* __restrict__ Qf,
    const u16* __restrict__ Kf, const u16* __restrict__ Vt,
    const float* __restrict__ llic, const float* __restrict__ SV,
    u16* __restrict__ Zb) {
  __shared__ short Ks[64 * 72];      // 9.2 KB
  __shared__ short Vs[64 * 72];      // 9.2 KB
  __shared__ short A2s[128 * 76];    // 19.5 KB
  __shared__ float rs_s[2][128];     // 1 KB   (total 38.9 KB, 2 blocks/CU)
  int tid = threadIdx.x;
  int lin = blockIdx.y * 16 + blockIdx.x;
  int wgid = (lin & 7) * 64 + (lin >> 3);   // XCD-chunked, bijective (512%8==0)
  int z = wgid >> 4, sblk = wgid & 15;
  int b = z >> 2, h = z & 3;
  const u16* Qb = Qf + (size_t)b * Ss * Ee + h * Dd;
  const u16* Kb = Kf + (size_t)b * Ss * Ee + h * Dd;
  const u16* VtZ = Vt + (size_t)z * Dd * Ss;
  const float* lz = llic + (size_t)z * Ss;
  int s0 = sblk * 128;
  int w = tid >> 6, lane = tid & 63, ml = lane & 15, q = lane >> 4;
  int sq = w >> 1, tq = w & 1;
  int wsd = sq << 5, wt = tq << 5;
  // Q A-frags (loop-invariant, 16 VGPR): rows s0+wsd+mt*16+ml
  bf16x8 qa[2][2];
#pragma unroll
  for (int ks = 0; ks < 2; ks++)
#pragma unroll
    for (int mt = 0; mt < 2; mt++)
      qa[ks][mt] = *reinterpret_cast<const bf16x8*>(
          Qb + (size_t)(s0 + wsd + mt * 16 + ml) * Ee + ks * 32 + q * 8);
  f32x4 acc2[4] = {};
  f32x4 rsv[2] = {};
  // staging: 256 threads per array, 4 threads/row, 16 shorts each
  int si = tid & 255, sr = si >> 2, sc = (si & 3) << 4;
  bool isK = tid < 256;
  const u16* kst = Kb + (size_t)sr * Ee + sc;    // + t0*Ee
  const u16* vst = VtZ + (size_t)sr * Ss + sc;   // + t0
  int sof = sr * 72 + sc;
  for (int t0 = 0; t0 < Ss; t0 += 64) {
    __syncthreads();
    if (isK) {
      *reinterpret_cast<bf16x8*>(&Ks[sof])     = *reinterpret_cast<const bf16x8*>(kst + (size_t)t0 * Ee);
      *reinterpret_cast<bf16x8*>(&Ks[sof + 8]) = *reinterpret_cast<const bf16x8*>(kst + (size_t)t0 * Ee + 8);
    } else {
      *reinterpret_cast<bf16x8*>(&Vs[sof])     = *reinterpret_cast<const bf16x8*>(vst + t0);
      *reinterpret_cast<bf16x8*>(&Vs[sof + 8]) = *reinterpret_cast<const bf16x8*>(vst + t0 + 8);
    }
    __syncthreads();
    // QK: wave (sq,tq) computes 32 s-rows x 32 t-cols
    f32x4 acc[2][2] = {};
#pragma unroll
    for (int ks = 0; ks < 2; ks++) {
      bf16x8 bf[2];
#pragma unroll
      for (int nt = 0; nt < 2; nt++)
        bf[nt] = *reinterpret_cast<const bf16x8*>(&Ks[(wt + nt * 16 + ml) * 72 + ks * 32 + q * 8]);
#pragma unroll
      for (int mt = 0; mt < 2; mt++)
#pragma unroll
        for (int nt = 0; nt < 2; nt++)
          acc[mt][nt] = __builtin_amdgcn_mfma_f32_16x16x32_bf16(qa[ks][mt], bf[nt], acc[mt][nt], 0, 0, 0);
    }
    // transform: e1 = exp2(S + llic) in (0,1]; A2' = expm1(e1) poly4
#pragma unroll
    for (int nt = 0; nt < 2; nt++) {
      float lcv = lz[t0 + wt + nt * 16 + ml];
#pragma unroll
      for (int mt = 0; mt < 2; mt++)
#pragma unroll
        for (int r = 0; r < 4; r++) {
          float e1 = ex2(acc[mt][nt][r] + lcv);
          float p = e1 * (1.f + e1 * (0.5f + e1 * (0.166666667f + e1 * 0.0416666667f)));
          rsv[mt][r] += p;
          union { float f; u32 u; } cv; cv.f = p;
          A2s[(wsd + mt * 16 + q * 4 + r) * 76 + wt + nt * 16 + ml] =
              (short)((cv.u + 0x8000u) >> 16);
        }
    }
    __syncthreads();
    // PV: wave w owns 16 s-rows x 64 d
#pragma unroll
    for (int ks = 0; ks < 2; ks++) {
      bf16x8 af2 = *reinterpret_cast<const bf16x8*>(&A2s[(w * 16 + ml) * 76 + ks * 32 + q * 8]);
      bf16x8 bv[4];
#pragma unroll
      for (int nt = 0; nt < 4; nt++)
        bv[nt] = *reinterpret_cast<const bf16x8*>(&Vs[(nt * 16 + ml) * 72 + ks * 32 + q * 8]);
#pragma unroll
      for (int nt = 0; nt < 4; nt++)
        acc2[nt] = __builtin_amdgcn_mfma_f32_16x16x32_bf16(af2, bv[nt], acc2[nt], 0, 0, 0);
    }
  }
  // row sums across the 16 col-lanes; two tq slots per row
#pragma unroll
  for (int mt = 0; mt < 2; mt++)
#pragma unroll
    for (int r = 0; r < 4; r++) {
      float v = rsv[mt][r];
      v += __shfl_xor(v, 1); v += __shfl_xor(v, 2);
      v += __shfl_xor(v, 4); v += __shfl_xor(v, 8);
      if (ml == 0) rs_s[tq][wsd + mt * 16 + q * 4 + r] = v;
    }
  __syncthreads();
  const float* SVz = SV + (size_t)z * Dd;
#pragma unroll
  for (int r = 0; r < 4; r++) {
    int row = w * 16 + q * 4 + r;
    float inv = 1.f / (2048.f + rs_s[0][row] + rs_s[1][row]);
#pragma unroll
    for (int nt = 0; nt < 4; nt++) {
      float o = (SVz[nt * 16 + ml] + acc2[nt][r]) * inv;
      Zb[(size_t)(b * Ss + s0 + row) * Ee + h * Dd + nt * 16 + ml] = f2bf(o);
    }
  }
}

// ---------------- ZF (MFMA bf16) + residual: x += Zb@Wz^T + bz; xb refresh ---
__global__ __launch_bounds__(256) void k_zfm(const u16* __restrict__ Zb,
    const u16* __restrict__ Wzb, const float* __restrict__ bzp,
    float* __restrict__ x, u16* __restrict__ xb, int mod) {
  __shared__ short Zs[128][72];
  __shared__ short Ws[128][72];
  int tid = threadIdx.x;
  int coff = blockIdx.x << 7;
  const u16* W = Wzb + (size_t)mod * 256 * 256;
  const float* bias = bzp + mod * Ee;
  int s0 = blockIdx.y * 128;
  int lr = tid >> 1, lc = (tid & 1) << 5;
  int w = tid >> 6, lane = tid & 63, ml = lane & 15, q = lane >> 4;
  int sh = (w >> 1) << 6, th = (w & 1) << 6;
  f32x4 acc[4][4] = {};
  for (int k0 = 0; k0 < 256; k0 += 64) {
#pragma unroll
    for (int hh = 0; hh < 4; hh++) {
      *reinterpret_cast<bf16x8*>(&Zs[lr][lc + hh * 8]) =
          *reinterpret_cast<const bf16x8*>(Zb + (size_t)(s0 + lr) * Ee + k0 + lc + hh * 8);
      *reinterpret_cast<bf16x8*>(&Ws[lr][lc + hh * 8]) =
          *reinterpret_cast<const bf16x8*>(W + (size_t)(coff + lr) * Ee + k0 + lc + hh * 8);
    }
    __syncthreads();
#pragma unroll
    for (int ks = 0; ks < 2; ks++) {
      bf16x8 af[4], bfr[4];
#pragma unroll
      for (int mt = 0; mt < 4; mt++)
        af[mt] = *reinterpret_cast<const bf16x8*>(&Zs[sh + mt * 16 + ml][ks * 32 + q * 8]);
#pragma unroll
      for (int nt = 0; nt < 4; nt++)
        bfr[nt] = *reinterpret_cast<const bf16x8*>(&Ws[th + nt * 16 + ml][ks * 32 + q * 8]);
#pragma unroll
      for (int mt = 0; mt < 4; mt++)
#pragma unroll
        for (int nt = 0; nt < 4; nt++)
          acc[mt][nt] = __builtin_amdgcn_mfma_f32_16x16x32_bf16(af[mt], bfr[nt], acc[mt][nt], 0, 0, 0);
    }
    __syncthreads();
  }
#pragma unroll
  for (int mt = 0; mt < 4; mt++)
#pragma unroll
    for (int nt = 0; nt < 4; nt++)
#pragma unroll
      for (int r = 0; r < 4; r++) {
        int gm = s0 + sh + mt * 16 + q * 4 + r;
        int gn = coff + th + nt * 16 + ml;
        float xv = x[(size_t)gm * Ee + gn] + acc[mt][nt][r] + bias[gn];
        x[(size_t)gm * Ee + gn] = xv;
        xb[(size_t)gm * Ee + gn] = f2bf(xv);
      }
}

// ---------------- final head: block = (c-chunk of 4096, 2 batches) -----------
__global__ __launch_bounds__(256) void k_final1(const float* __restrict__ x,
    const float* __restrict__ Wo, float* __restrict__ part) {
  int cb = blockIdx.x;                 // 0..127 chunk of 4096 floats
  int b0 = blockIdx.y * 2;             // 0,2,4,6
  int tid = threadIdx.x;
  int w = tid >> 6, lane = tid & 63;
  float acc[2][16];
#pragma unroll
  for (int bb = 0; bb < 2; bb++)
#pragma unroll
    for (int l = 0; l < 16; l++) acc[bb][l] = 0.f;
  const float4* x4 = reinterpret_cast<const float4*>(x);
  const float4* w4 = reinterpret_cast<const float4*>(Wo);
#pragma unroll
  for (int it = 0; it < 4; it++) {
    int i = it * 256 + tid;
    float4 xv0 = x4[(size_t)(b0 + 0) * 131072 + cb * 1024 + i];
    float4 xv1 = x4[(size_t)(b0 + 1) * 131072 + cb * 1024 + i];
#pragma unroll
    for (int l = 0; l < 16; l++) {
      float4 wv = w4[(size_t)l * 131072 + cb * 1024 + i];
      acc[0][l] += xv0.x * wv.x + xv0.y * wv.y + xv0.z * wv.z + xv0.w * wv.w;
      acc[1][l] += xv1.x * wv.x + xv1.y * wv.y + xv1.z * wv.z + xv1.w * wv.w;
    }
  }
  __shared__ float red[4][32];
#pragma unroll
  for (int bb = 0; bb < 2; bb++)
#pragma unroll
    for (int l = 0; l < 16; l++) {
      float v = acc[bb][l];
#pragma unroll
      for (int off = 1; off < 64; off <<= 1) v += __shfl_xor(v, off);
      if (lane == 0) red[w][bb * 16 + l] = v;
    }
  __syncthreads();
  if (tid < 32) {
    int lb = tid >> 4, l = tid & 15;
    float s = red[0][tid] + red[1][tid] + red[2][tid] + red[3][tid];
    part[(size_t)((b0 + lb) * 16 + l) * 128 + cb] = s;
  }
}

__global__ void k_final2(const float* __restrict__ part, const float* __restrict__ bo,
                         float* __restrict__ out) {
  int idx = threadIdx.x;   // 128 = 8*16
  float s = 0.f;
  for (int c = 0; c < 128; c++) s += part[(size_t)idx * 128 + c];
  s += bo[idx & 15];
  out[idx] = 1.f / (1.f + __expf(-s));
}

extern "C" void kernel_launch(void* const* d_in, const int* in_sizes, int n_in,
                              void* d_out, int out_size, void* d_ws, size_t ws_size,
                              hipStream_t stream) {
  const int*   seqs = (const int*)d_in[0];
  const float* emb  = (const float*)d_in[1];
  const float* Wq   = (const float*)d_in[2];
  const float* bq   = (const float*)d_in[3];
  const float* Wk   = (const float*)d_in[4];
  const float* bk   = (const float*)d_in[5];
  const float* Wv   = (const float*)d_in[6];
  const float* bv   = (const float*)d_in[7];
  const float* Wz   = (const float*)d_in[8];
  const float* bz   = (const float*)d_in[9];
  const float* Wo   = (const float*)d_in[10];
  const float* bo   = (const float*)d_in[11];
  float* out = (float*)d_out;
  float* ws  = (float*)d_ws;

  float* x    = ws;                                    // 4,194,304 f
  u16*   xb   = (u16*)(ws + 4194304);
  u16*   Qf   = (u16*)(ws + 6291456);
  u16*   Kf   = (u16*)(ws + 8388608);
  u16*   Vf   = (u16*)(ws + 10485760);
  u16*   Vt   = (u16*)(ws + 12582912);
  u16*   Zb   = (u16*)(ws + 14680064);
  float* SV   = ws + 16777216;                         // 2,048 f
  u16*   Wqb  = (u16*)(ws + 16787456);
  u16*   Wkb  = (u16*)(ws + 16852992);
  u16*   Wvb  = (u16*)(ws + 16918528);
  u16*   Wzb  = (u16*)(ws + 16984064);
  float* llic = ws + 17049600;                         // 65,536 f (csums then -log2)
  float* part = ws + 6291456;                          // reuses Qf area post-modules

  k_gather<<<(Bb * Ss * 64) / 256, 256, 0, stream>>>(seqs, emb, x, xb);
  k_w2b<<<131072 / 1024, 256, 0, stream>>>(Wq, Wqb);
  k_w2b<<<131072 / 1024, 256, 0, stream>>>(Wk, Wkb);
  k_w2b<<<131072 / 1024, 256, 0, stream>>>(Wv, Wvb);
  k_w2b<<<131072 / 1024, 256, 0, stream>>>(Wz, Wzb);

  for (int m = 0; m < 2; m++) {
    k_qkvm<<<dim3(6, 128), 256, 0, stream>>>(xb, Wqb, Wkb, Wvb, bq, bk, bv, Qf, Kf, Vf, m);
    k_vt<<<dim3(32, 32), 256, 0, stream>>>(Vf, Vt);
    k_vsum<<<dim3(16, 32), 256, 0, stream>>>(Vt, SV, llic);
    k_csum<<<dim3(16, 2, 32), 256, 0, stream>>>(Qf, Kf, llic);
    k_llog<<<256, 256, 0, stream>>>(llic);
    k_att<<<dim3(16, 32), 512, 0, stream>>>(Qf, Kf, Vt, llic, SV, Zb);
    k_zfm<<<dim3(2, 128), 256, 0, stream>>>(Zb, Wzb, bz, x, xb, m);
  }

  k_final1<<<dim3(128, 4), 256, 0, stream>>>(x, Wo, part);
  k_final2<<<1, 128, 0, stream>>>(part, bo, out);
}

// Round 9
// 498.143 us; speedup vs baseline: 1.4726x; 1.0164x over previous
//
#include <hip/hip_runtime.h>
#include <math.h>

#define Bb 8
#define Ss 2048
#define Ee 256
#define Hh 4
#define Dd 64

typedef unsigned short u16;
typedef unsigned int u32;
typedef __attribute__((ext_vector_type(8))) short bf16x8;
typedef __attribute__((ext_vector_type(4))) float f32x4;
typedef __attribute__((ext_vector_type(16))) float f32x16;

__device__ __forceinline__ u16 f2bf(float f) {
  union { float f; u32 u; } c; c.f = f;
  return (u16)((c.u + 0x7FFFu + ((c.u >> 16) & 1u)) >> 16);
}
__device__ __forceinline__ float bf2f(u16 u) {
  union { u32 u; float f; } c; c.u = ((u32)u) << 16;
  return c.f;
}
__device__ __forceinline__ float bf2fs(short s) { return bf2f((u16)s); }
__device__ __forceinline__ float ex2(float x) { return __builtin_amdgcn_exp2f(x); }

// ---------------- weight fp32 -> bf16 convert ----------------
__global__ __launch_bounds__(256) void k_w2b(const float* __restrict__ src,
                                             u16* __restrict__ dst) {
  int idx = (blockIdx.x * 256 + threadIdx.x) * 4;
  float4 v = *reinterpret_cast<const float4*>(src + idx);
  ushort4 o;
  o.x = f2bf(v.x); o.y = f2bf(v.y); o.z = f2bf(v.z); o.w = f2bf(v.w);
  *reinterpret_cast<ushort4*>(dst + idx) = o;
}

// ---------------- embedding gather (fp32 x + bf16 xb) ----------------
__global__ __launch_bounds__(256) void k_gather(const int* __restrict__ seqs,
                                                const float* __restrict__ emb,
                                                float* __restrict__ x,
                                                u16* __restrict__ xb) {
  int idx = blockIdx.x * 256 + threadIdx.x;
  int row = idx >> 6, c4 = idx & 63;
  int tok = seqs[row];
  float4 v = reinterpret_cast<const float4*>(emb)[(size_t)tok * 64 + c4];
  reinterpret_cast<float4*>(x)[(size_t)row * 64 + c4] = v;
  ushort4 o;
  o.x = f2bf(v.x); o.y = f2bf(v.y); o.z = f2bf(v.z); o.w = f2bf(v.w);
  reinterpret_cast<ushort4*>(xb)[(size_t)row * 64 + c4] = o;
}

// ---------------- QKV projection (MFMA bf16): relu(xb@W^T+b) -> bf16 --------
// Q output pre-scaled by log2(e)/16 (folds attention scale AND exp->exp2).
__global__ __launch_bounds__(256) void k_qkvm(const u16* __restrict__ xb,
    const u16* __restrict__ Wqb, const u16* __restrict__ Wkb, const u16* __restrict__ Wvb,
    const float* __restrict__ bq, const float* __restrict__ bk, const float* __restrict__ bv,
    u16* __restrict__ Qf, u16* __restrict__ Kf, u16* __restrict__ Vf, int mod) {
  __shared__ short Xs[128][72];
  __shared__ short Ws[128][72];
  int tid = threadIdx.x;
  int bn = blockIdx.x;
  int arr = bn >> 1, coff = (bn & 1) << 7;
  const u16* W = (arr == 0 ? Wqb : arr == 1 ? Wkb : Wvb) + (size_t)mod * 256 * 256;
  const float* bias = (arr == 0 ? bq : arr == 1 ? bk : bv) + mod * 256;
  u16* Out = (arr == 0 ? Qf : arr == 1 ? Kf : Vf);
  float oscale = (arr == 0) ? 0.0625f * 1.44269504f : 1.0f;
  int s0 = blockIdx.y * 128;
  int lr = tid >> 1, lc = (tid & 1) << 5;
  int w = tid >> 6, lane = tid & 63, ml = lane & 15, q = lane >> 4;
  int sh = (w >> 1) << 6, th = (w & 1) << 6;
  f32x4 acc[4][4] = {};
  for (int k0 = 0; k0 < 256; k0 += 64) {
#pragma unroll
    for (int hh = 0; hh < 4; hh++) {
      *reinterpret_cast<bf16x8*>(&Xs[lr][lc + hh * 8]) =
          *reinterpret_cast<const bf16x8*>(xb + (size_t)(s0 + lr) * Ee + k0 + lc + hh * 8);
      *reinterpret_cast<bf16x8*>(&Ws[lr][lc + hh * 8]) =
          *reinterpret_cast<const bf16x8*>(W + (size_t)(coff + lr) * Ee + k0 + lc + hh * 8);
    }
    __syncthreads();
#pragma unroll
    for (int ks = 0; ks < 2; ks++) {
      bf16x8 af[4], bfr[4];
#pragma unroll
      for (int mt = 0; mt < 4; mt++)
        af[mt] = *reinterpret_cast<const bf16x8*>(&Xs[sh + mt * 16 + ml][ks * 32 + q * 8]);
#pragma unroll
      for (int nt = 0; nt < 4; nt++)
        bfr[nt] = *reinterpret_cast<const bf16x8*>(&Ws[th + nt * 16 + ml][ks * 32 + q * 8]);
#pragma unroll
      for (int mt = 0; mt < 4; mt++)
#pragma unroll
        for (int nt = 0; nt < 4; nt++)
          acc[mt][nt] = __builtin_amdgcn_mfma_f32_16x16x32_bf16(af[mt], bfr[nt], acc[mt][nt], 0, 0, 0);
    }
    __syncthreads();
  }
#pragma unroll
  for (int mt = 0; mt < 4; mt++)
#pragma unroll
    for (int nt = 0; nt < 4; nt++)
#pragma unroll
      for (int r = 0; r < 4; r++) {
        int gm = s0 + sh + mt * 16 + q * 4 + r;
        int cc = coff + th + nt * 16 + ml;
        float v = acc[mt][nt][r] + bias[cc];
        v = (v > 0.f ? v : 0.f) * oscale;
        Out[(size_t)gm * Ee + cc] = f2bf(v);
      }
}

// ---------------- V transpose: Vf[b][t][h*64+d] -> Vt[(b*4+h)*64+d][t] -------
__global__ __launch_bounds__(256) void k_vt(const u16* __restrict__ Vf,
                                            u16* __restrict__ Vt) {
  __shared__ u16 T[64][72];
  int tid = threadIdx.x;
  int t0 = blockIdx.x * 64;
  int z = blockIdx.y;
  int b = z >> 2, h = z & 3;
  int lr = tid >> 2, lc = (tid & 3) << 4;
#pragma unroll
  for (int hh = 0; hh < 2; hh++) {
    bf16x8 v = *reinterpret_cast<const bf16x8*>(
        Vf + (size_t)(b * Ss + t0 + lr) * Ee + h * Dd + lc + hh * 8);
#pragma unroll
    for (int j = 0; j < 8; j++) T[lr][lc + hh * 8 + j] = (u16)v[j];
  }
  __syncthreads();
#pragma unroll
  for (int j = 0; j < 16; j++) {
    Vt[((size_t)z * Dd + lr) * Ss + t0 + lc + j] = T[lc + j][lr];
  }
}

// ---------------- SV[z][d] = sum_t Vt[z*64+d][t]; also zero csums ------------
__global__ __launch_bounds__(256) void k_vsum(const u16* __restrict__ Vt,
                                              float* __restrict__ SV,
                                              float* __restrict__ csums) {
  int gi = (blockIdx.y * gridDim.x + blockIdx.x) * 256 + threadIdx.x;
  if (gi < 32 * Ss) csums[gi] = 0.f;
  int z = blockIdx.y;
  int d = blockIdx.x * 4 + (threadIdx.x >> 6);
  int lane = threadIdx.x & 63;
  const u16* row = Vt + ((size_t)z * Dd + d) * Ss;
  float s = 0.f;
#pragma unroll
  for (int it = 0; it < 4; it++) {
    bf16x8 v = *reinterpret_cast<const bf16x8*>(row + it * 512 + lane * 8);
#pragma unroll
    for (int j = 0; j < 8; j++) s += bf2fs(v[j]);
  }
#pragma unroll
  for (int off = 32; off; off >>= 1) s += __shfl_xor(s, off);
  if (lane == 0) SV[(size_t)z * Dd + d] = s;
}

// ---------------- pass 1: csums[t] += sum_s exp2(S) (barrier-free loop) ------
__global__ __launch_bounds__(256, 4) void k_csum(const u16* __restrict__ Qf,
    const u16* __restrict__ Kf, float* __restrict__ csums) {
  __shared__ float csm[2][128];
  int tid = threadIdx.x;
  int lin = (blockIdx.z * 2 + blockIdx.y) * 16 + blockIdx.x;
  int wgid = (lin & 7) * 128 + (lin >> 3);   // XCD-chunked, bijective (1024 % 8 == 0)
  int ttile = wgid & 15, shalf = (wgid >> 4) & 1, z = wgid >> 5;
  int b = z >> 2, h = z & 3;
  const u16* Qb = Qf + (size_t)b * Ss * Ee + h * Dd;
  const u16* Kb = Kf + (size_t)b * Ss * Ee + h * Dd;
  int w = tid >> 6, lane = tid & 63, l31 = lane & 31, hi = lane >> 5;
  int sh = (w >> 1) << 6, th = (w & 1) << 6;
  const u16* kr = Kb + (size_t)(ttile * 128 + th + l31) * Ee + hi * 8;
  bf16x8 kb[2][4];
#pragma unroll
  for (int tt = 0; tt < 2; tt++)
#pragma unroll
    for (int kk = 0; kk < 4; kk++)
      kb[tt][kk] = *reinterpret_cast<const bf16x8*>(kr + (size_t)tt * 32 * Ee + kk * 16);
  const u16* Qr0 = Qb + (size_t)(shalf * 1024 + sh + l31) * Ee + hi * 8;
  bf16x8 qc0 = *reinterpret_cast<const bf16x8*>(Qr0);
  bf16x8 qc1 = *reinterpret_cast<const bf16x8*>(Qr0 + 16);
  bf16x8 qc2 = *reinterpret_cast<const bf16x8*>(Qr0 + 32);
  bf16x8 qc3 = *reinterpret_cast<const bf16x8*>(Qr0 + 48);
  float cs0 = 0.f, cs1 = 0.f;
  for (int it = 0; it < 16; it++) {
    int itn = (it + 1) & 15;
    const u16* qnp = Qr0 + (size_t)(((itn >> 1) << 7) + ((itn & 1) << 5)) * Ee;
    bf16x8 qn0 = *reinterpret_cast<const bf16x8*>(qnp);
    bf16x8 qn1 = *reinterpret_cast<const bf16x8*>(qnp + 16);
    bf16x8 qn2 = *reinterpret_cast<const bf16x8*>(qnp + 32);
    bf16x8 qn3 = *reinterpret_cast<const bf16x8*>(qnp + 48);
    f32x16 a0 = {}, a1 = {};
    __builtin_amdgcn_s_setprio(1);
    a0 = __builtin_amdgcn_mfma_f32_32x32x16_bf16(qc0, kb[0][0], a0, 0, 0, 0);
    a1 = __builtin_amdgcn_mfma_f32_32x32x16_bf16(qc0, kb[1][0], a1, 0, 0, 0);
    a0 = __builtin_amdgcn_mfma_f32_32x32x16_bf16(qc1, kb[0][1], a0, 0, 0, 0);
    a1 = __builtin_amdgcn_mfma_f32_32x32x16_bf16(qc1, kb[1][1], a1, 0, 0, 0);
    a0 = __builtin_amdgcn_mfma_f32_32x32x16_bf16(qc2, kb[0][2], a0, 0, 0, 0);
    a1 = __builtin_amdgcn_mfma_f32_32x32x16_bf16(qc2, kb[1][2], a1, 0, 0, 0);
    a0 = __builtin_amdgcn_mfma_f32_32x32x16_bf16(qc3, kb[0][3], a0, 0, 0, 0);
    a1 = __builtin_amdgcn_mfma_f32_32x32x16_bf16(qc3, kb[1][3], a1, 0, 0, 0);
    __builtin_amdgcn_s_setprio(0);
#pragma unroll
    for (int j = 0; j < 16; j++) { cs0 += ex2(a0[j]); cs1 += ex2(a1[j]); }
    qc0 = qn0; qc1 = qn1; qc2 = qn2; qc3 = qn3;
  }
  cs0 += __shfl_xor(cs0, 32);
  cs1 += __shfl_xor(cs1, 32);
  if (lane < 32) {
    csm[w >> 1][th + l31] = cs0;
    csm[w >> 1][th + 32 + l31] = cs1;
  }
  __syncthreads();
  if (tid < 128)
    atomicAdd(&csums[(size_t)z * Ss + ttile * 128 + tid], csm[0][tid] + csm[1][tid]);
}

// ---------------- csums -> llic = -log2(csums), in place ---------------------
__global__ void k_llog(float* __restrict__ llic) {
  int i = blockIdx.x * 256 + threadIdx.x;
  llic[i] = -__log2f(llic[i]);
}

// ---------------- pass 2: fused attention (r8 + dbuf K/V + 2 barriers) -------
// grid (16 s-tiles of 128 rows, 32 z), 512 threads, 2 blocks/CU.
// Per 64-t chunk: QK (reads Ks[p]) -> transform -> A2s write -> barrier ->
// PV (reads A2s, Vs[p]) + write prefetched K/V regs into buf p^1 + issue
// loads for t0+128 -> barrier. Staging latency hides under QK+transform (T14).
// A2s stride 78 (odd bank offset) to kill systematic write conflicts.
__global__ __launch_bounds__(512, 4) void k_att(const u16* __restrict__ Qf,
    const u16* __restrict__ Kf, const u16* __restrict__ Vt,
    const float* __restrict__ llic, const float* __restrict__ SV,
    u16* __restrict__ Zb) {
  __shared__ short Ks[2][64 * 72];   // 18.4 KB
  __shared__ short Vs[2][64 * 72];   // 18.4 KB
  __shared__ short A2s[128 * 78];    // 20.0 KB
  __shared__ float rs_s[2][128];     // 1 KB   (total 57.8 KB, 2 blocks/CU)
  int tid = threadIdx.x;
  int lin = blockIdx.y * 16 + blockIdx.x;
  int wgid = (lin & 7) * 64 + (lin >> 3);   // XCD-chunked, bijective (512%8==0)
  int z = wgid >> 4, sblk = wgid & 15;
  int b = z >> 2, h = z & 3;
  const u16* Qb = Qf + (size_t)b * Ss * Ee + h * Dd;
  const u16* Kb = Kf + (size_t)b * Ss * Ee + h * Dd;
  const u16* VtZ = Vt + (size_t)z * Dd * Ss;
  const float* lz = llic + (size_t)z * Ss;
  int s0 = sblk * 128;
  int w = tid >> 6, lane = tid & 63, ml = lane & 15, q = lane >> 4;
  int sq = w >> 1, tq = w & 1;
  int wsd = sq << 5, wt = tq << 5;
  // Q A-frags (loop-invariant, 16 VGPR)
  bf16x8 qa[2][2];
#pragma unroll
  for (int ks = 0; ks < 2; ks++)
#pragma unroll
    for (int mt = 0; mt < 2; mt++)
      qa[ks][mt] = *reinterpret_cast<const bf16x8*>(
          Qb + (size_t)(s0 + wsd + mt * 16 + ml) * Ee + ks * 32 + q * 8);
  f32x4 acc2[4] = {};
  f32x4 rsv[2] = {};
  // staging: 256 threads per array, 4 threads/row, 16 shorts each
  int si = tid & 255, sr = si >> 2, sc = (si & 3) << 4;
  bool isK = tid < 256;
  const u16* kst = Kb + (size_t)sr * Ee + sc;    // + t0*Ee
  const u16* vst = VtZ + (size_t)sr * Ss + sc;   // + t0
  int sof = sr * 72 + sc;
  // prologue: stage chunk 0 directly; prefetch chunk 1 into regs
  bf16x8 pf0, pf1;
  if (isK) {
    *reinterpret_cast<bf16x8*>(&Ks[0][sof])     = *reinterpret_cast<const bf16x8*>(kst);
    *reinterpret_cast<bf16x8*>(&Ks[0][sof + 8]) = *reinterpret_cast<const bf16x8*>(kst + 8);
    pf0 = *reinterpret_cast<const bf16x8*>(kst + (size_t)64 * Ee);
    pf1 = *reinterpret_cast<const bf16x8*>(kst + (size_t)64 * Ee + 8);
  } else {
    *reinterpret_cast<bf16x8*>(&Vs[0][sof])     = *reinterpret_cast<const bf16x8*>(vst);
    *reinterpret_cast<bf16x8*>(&Vs[0][sof + 8]) = *reinterpret_cast<const bf16x8*>(vst + 8);
    pf0 = *reinterpret_cast<const bf16x8*>(vst + 64);
    pf1 = *reinterpret_cast<const bf16x8*>(vst + 64 + 8);
  }
  __syncthreads();

#define CHUNK(T0, PB) { \
    /* QK: wave (sq,tq) computes 32 s-rows x 32 t-cols from Ks[PB] */ \
    f32x4 acc[2][2] = {}; \
    _Pragma("unroll") \
    for (int ks = 0; ks < 2; ks++) { \
      bf16x8 bfk[2]; \
      _Pragma("unroll") \
      for (int nt = 0; nt < 2; nt++) \
        bfk[nt] = *reinterpret_cast<const bf16x8*>(&Ks[PB][(wt + nt * 16 + ml) * 72 + ks * 32 + q * 8]); \
      _Pragma("unroll") \
      for (int mt = 0; mt < 2; mt++) \
        _Pragma("unroll") \
        for (int nt = 0; nt < 2; nt++) \
          acc[mt][nt] = __builtin_amdgcn_mfma_f32_16x16x32_bf16(qa[ks][mt], bfk[nt], acc[mt][nt], 0, 0, 0); \
    } \
    /* transform: e1 = exp2(S + llic); A2' = expm1(e1) poly4 */ \
    _Pragma("unroll") \
    for (int nt = 0; nt < 2; nt++) { \
      float lcv = lz[(T0) + wt + nt * 16 + ml]; \
      _Pragma("unroll") \
      for (int mt = 0; mt < 2; mt++) \
        _Pragma("unroll") \
        for (int r = 0; r < 4; r++) { \
          float e1 = ex2(acc[mt][nt][r] + lcv); \
          float p = e1 * (1.f + e1 * (0.5f + e1 * (0.166666667f + e1 * 0.0416666667f))); \
          rsv[mt][r] += p; \
          union { float f; u32 u; } cv; cv.f = p; \
          A2s[(wsd + mt * 16 + q * 4 + r) * 78 + wt + nt * 16 + ml] = \
              (short)((cv.u + 0x8000u) >> 16); \
        } \
    } \
    __syncthreads(); \
    /* PV: wave w owns 16 s-rows x 64 d (reads A2s + Vs[PB]) */ \
    _Pragma("unroll") \
    for (int ks = 0; ks < 2; ks++) { \
      bf16x8 af2 = *reinterpret_cast<const bf16x8*>(&A2s[(w * 16 + ml) * 78 + ks * 32 + q * 8]); \
      bf16x8 bvv[4]; \
      _Pragma("unroll") \
      for (int nt = 0; nt < 4; nt++) \
        bvv[nt] = *reinterpret_cast<const bf16x8*>(&Vs[PB][(nt * 16 + ml) * 72 + ks * 32 + q * 8]); \
      _Pragma("unroll") \
      for (int nt = 0; nt < 4; nt++) \
        acc2[nt] = __builtin_amdgcn_mfma_f32_16x16x32_bf16(af2, bvv[nt], acc2[nt], 0, 0, 0); \
    } \
    /* write prefetched chunk T0+64 into buf PB^1; issue loads for T0+128 */ \
    { \
      int tn = ((T0) + 128) & (Ss - 1); \
      if (isK) { \
        *reinterpret_cast<bf16x8*>(&Ks[(PB) ^ 1][sof])     = pf0; \
        *reinterpret_cast<bf16x8*>(&Ks[(PB) ^ 1][sof + 8]) = pf1; \
        pf0 = *reinterpret_cast<const bf16x8*>(kst + (size_t)tn * Ee); \
        pf1 = *reinterpret_cast<const bf16x8*>(kst + (size_t)tn * Ee + 8); \
      } else { \
        *reinterpret_cast<bf16x8*>(&Vs[(PB) ^ 1][sof])     = pf0; \
        *reinterpret_cast<bf16x8*>(&Vs[(PB) ^ 1][sof + 8]) = pf1; \
        pf0 = *reinterpret_cast<const bf16x8*>(vst + tn); \
        pf1 = *reinterpret_cast<const bf16x8*>(vst + tn + 8); \
      } \
    } \
    __syncthreads(); \
  }

  for (int t0 = 0; t0 < Ss; t0 += 128) {
    CHUNK(t0, 0);
    CHUNK(t0 + 64, 1);
  }
#undef CHUNK

  // row sums across the 16 col-lanes; two tq slots per row
#pragma unroll
  for (int mt = 0; mt < 2; mt++)
#pragma unroll
    for (int r = 0; r < 4; r++) {
      float v = rsv[mt][r];
      v += __shfl_xor(v, 1); v += __shfl_xor(v, 2);
      v += __shfl_xor(v, 4); v += __shfl_xor(v, 8);
      if (ml == 0) rs_s[tq][wsd + mt * 16 + q * 4 + r] = v;
    }
  __syncthreads();
  const float* SVz = SV + (size_t)z * Dd;
#pragma unroll
  for (int r = 0; r < 4; r++) {
    int row = w * 16 + q * 4 + r;
    float inv = 1.f / (2048.f + rs_s[0][row] + rs_s[1][row]);
#pragma unroll
    for (int nt = 0; nt < 4; nt++) {
      float o = (SVz[nt * 16 + ml] + acc2[nt][r]) * inv;
      Zb[(size_t)(b * Ss + s0 + row) * Ee + h * Dd + nt * 16 + ml] = f2bf(o);
    }
  }
}

// ---------------- ZF (MFMA bf16) + residual: x += Zb@Wz^T + bz; xb refresh ---
__global__ __launch_bounds__(256) void k_zfm(const u16* __restrict__ Zb,
    const u16* __restrict__ Wzb, const float* __restrict__ bzp,
    float* __restrict__ x, u16* __restrict__ xb, int mod) {
  __shared__ short Zs[128][72];
  __shared__ short Ws[128][72];
  int tid = threadIdx.x;
  int coff = blockIdx.x << 7;
  const u16* W = Wzb + (size_t)mod * 256 * 256;
  const float* bias = bzp + mod * Ee;
  int s0 = blockIdx.y * 128;
  int lr = tid >> 1, lc = (tid & 1) << 5;
  int w = tid >> 6, lane = tid & 63, ml = lane & 15, q = lane >> 4;
  int sh = (w >> 1) << 6, th = (w & 1) << 6;
  f32x4 acc[4][4] = {};
  for (int k0 = 0; k0 < 256; k0 += 64) {
#pragma unroll
    for (int hh = 0; hh < 4; hh++) {
      *reinterpret_cast<bf16x8*>(&Zs[lr][lc + hh * 8]) =
          *reinterpret_cast<const bf16x8*>(Zb + (size_t)(s0 + lr) * Ee + k0 + lc + hh * 8);
      *reinterpret_cast<bf16x8*>(&Ws[lr][lc + hh * 8]) =
          *reinterpret_cast<const bf16x8*>(W + (size_t)(coff + lr) * Ee + k0 + lc + hh * 8);
    }
    __syncthreads();
#pragma unroll
    for (int ks = 0; ks < 2; ks++) {
      bf16x8 af[4], bfr[4];
#pragma unroll
      for (int mt = 0; mt < 4; mt++)
        af[mt] = *reinterpret_cast<const bf16x8*>(&Zs[sh + mt * 16 + ml][ks * 32 + q * 8]);
#pragma unroll
      for (int nt = 0; nt < 4; nt++)
        bfr[nt] = *reinterpret_cast<const bf16x8*>(&Ws[th + nt * 16 + ml][ks * 32 + q * 8]);
#pragma unroll
      for (int mt = 0; mt < 4; mt++)
#pragma unroll
        for (int nt = 0; nt < 4; nt++)
          acc[mt][nt] = __builtin_amdgcn_mfma_f32_16x16x32_bf16(af[mt], bfr[nt], acc[mt][nt], 0, 0, 0);
    }
    __syncthreads();
  }
#pragma unroll
  for (int mt = 0; mt < 4; mt++)
#pragma unroll
    for (int nt = 0; nt < 4; nt++)
#pragma unroll
      for (int r = 0; r < 4; r++) {
        int gm = s0 + sh + mt * 16 + q * 4 + r;
        int gn = coff + th + nt * 16 + ml;
        float xv = x[(size_t)gm * Ee + gn] + acc[mt][nt][r] + bias[gn];
        x[(size_t)gm * Ee + gn] = xv;
        xb[(size_t)gm * Ee + gn] = f2bf(xv);
      }
}

// ---------------- final head: block = (c-chunk of 4096, 2 batches) -----------
__global__ __launch_bounds__(256) void k_final1(const float* __restrict__ x,
    const float* __restrict__ Wo, float* __restrict__ part) {
  int cb = blockIdx.x;                 // 0..127 chunk of 4096 floats
  int b0 = blockIdx.y * 2;             // 0,2,4,6
  int tid = threadIdx.x;
  int w = tid >> 6, lane = tid & 63;
  float acc[2][16];
#pragma unroll
  for (int bb = 0; bb < 2; bb++)
#pragma unroll
    for (int l = 0; l < 16; l++) acc[bb][l] = 0.f;
  const float4* x4 = reinterpret_cast<const float4*>(x);
  const float4* w4 = reinterpret_cast<const float4*>(Wo);
#pragma unroll
  for (int it = 0; it < 4; it++) {
    int i = it * 256 + tid;
    float4 xv0 = x4[(size_t)(b0 + 0) * 131072 + cb * 1024 + i];
    float4 xv1 = x4[(size_t)(b0 + 1) * 131072 + cb * 1024 + i];
#pragma unroll
    for (int l = 0; l < 16; l++) {
      float4 wv = w4[(size_t)l * 131072 + cb * 1024 + i];
      acc[0][l] += xv0.x * wv.x + xv0.y * wv.y + xv0.z * wv.z + xv0.w * wv.w;
      acc[1][l] += xv1.x * wv.x + xv1.y * wv.y + xv1.z * wv.z + xv1.w * wv.w;
    }
  }
  __shared__ float red[4][32];
#pragma unroll
  for (int bb = 0; bb < 2; bb++)
#pragma unroll
    for (int l = 0; l < 16; l++) {
      float v = acc[bb][l];
#pragma unroll
      for (int off = 1; off < 64; off <<= 1) v += __shfl_xor(v, off);
      if (lane == 0) red[w][bb * 16 + l] = v;
    }
  __syncthreads();
  if (tid < 32) {
    int lb = tid >> 4, l = tid & 15;
    float s = red[0][tid] + red[1][tid] + red[2][tid] + red[3][tid];
    part[(size_t)((b0 + lb) * 16 + l) * 128 + cb] = s;
  }
}

__global__ void k_final2(const float* __restrict__ part, const float* __restrict__ bo,
                         float* __restrict__ out) {
  int idx = threadIdx.x;   // 128 = 8*16
  float s = 0.f;
  for (int c = 0; c < 128; c++) s += part[(size_t)idx * 128 + c];
  s += bo[idx & 15];
  out[idx] = 1.f / (1.f + __expf(-s));
}

extern "C" void kernel_launch(void* const* d_in, const int* in_sizes, int n_in,
                              void* d_out, int out_size, void* d_ws, size_t ws_size,
                              hipStream_t stream) {
  const int*   seqs = (const int*)d_in[0];
  const float* emb  = (const float*)d_in[1];
  const float* Wq   = (const float*)d_in[2];
  const float* bq   = (const float*)d_in[3];
  const float* Wk   = (const float*)d_in[4];
  const float* bk   = (const float*)d_in[5];
  const float* Wv   = (const float*)d_in[6];
  const float* bv   = (const float*)d_in[7];
  const float* Wz   = (const float*)d_in[8];
  const float* bz   = (const float*)d_in[9];
  const float* Wo   = (const float*)d_in[10];
  const float* bo   = (const float*)d_in[11];
  float* out = (float*)d_out;
  float* ws  = (float*)d_ws;

  float* x    = ws;                                    // 4,194,304 f
  u16*   xb   = (u16*)(ws + 4194304);
  u16*   Qf   = (u16*)(ws + 6291456);
  u16*   Kf   = (u16*)(ws + 8388608);
  u16*   Vf   = (u16*)(ws + 10485760);
  u16*   Vt   = (u16*)(ws + 12582912);
  u16*   Zb   = (u16*)(ws + 14680064);
  float* SV   = ws + 16777216;                         // 2,048 f
  u16*   Wqb  = (u16*)(ws + 16787456);
  u16*   Wkb  = (u16*)(ws + 16852992);
  u16*   Wvb  = (u16*)(ws + 16918528);
  u16*   Wzb  = (u16*)(ws + 16984064);
  float* llic = ws + 17049600;                         // 65,536 f (csums then -log2)
  float* part = ws + 6291456;                          // reuses Qf area post-modules

  k_gather<<<(Bb * Ss * 64) / 256, 256, 0, stream>>>(seqs, emb, x, xb);
  k_w2b<<<131072 / 1024, 256, 0, stream>>>(Wq, Wqb);
  k_w2b<<<131072 / 1024, 256, 0, stream>>>(Wk, Wkb);
  k_w2b<<<131072 / 1024, 256, 0, stream>>>(Wv, Wvb);
  k_w2b<<<131072 / 1024, 256, 0, stream>>>(Wz, Wzb);

  for (int m = 0; m < 2; m++) {
    k_qkvm<<<dim3(6, 128), 256, 0, stream>>>(xb, Wqb, Wkb, Wvb, bq, bk, bv, Qf, Kf, Vf, m);
    k_vt<<<dim3(32, 32), 256, 0, stream>>>(Vf, Vt);
    k_vsum<<<dim3(16, 32), 256, 0, stream>>>(Vt, SV, llic);
    k_csum<<<dim3(16, 2, 32), 256, 0, stream>>>(Qf, Kf, llic);
    k_llog<<<256, 256, 0, stream>>>(llic);
    k_att<<<dim3(16, 32), 512, 0, stream>>>(Qf, Kf, Vt, llic, SV, Zb);
    k_zfm<<<dim3(2, 128), 256, 0, stream>>>(Zb, Wzb, bz, x, xb, m);
  }

  k_final1<<<dim3(128, 4), 256, 0, stream>>>(x, Wo, part);
  k_final2<<<1, 128, 0, stream>>>(part, bo, out);
}